// Round 5
// baseline (966.001 us; speedup 1.0000x reference)
//
#include <hip/hip_runtime.h>
#include <hip/hip_bf16.h>

#define BB 4
#define LL 256
#define PP 1024
#define DD 512
#define HH 8
#define HD 64
#define NRBF 50

// ---------------------------------------------------------------------------
// dtype helpers (inputs are fp32 per reference; bf16 fallback kept for safety)
// ---------------------------------------------------------------------------
__device__ __forceinline__ float bf2f(unsigned short u) {
  return __uint_as_float((unsigned)u << 16);
}

__device__ __forceinline__ float ldf(const void* p, size_t i, bool f32) {
  if (f32) return ((const float*)p)[i];
  return bf2f(((const unsigned short*)p)[i]);
}

__device__ __forceinline__ float4 ld4e(const void* p, size_t i, bool f32) {
  if (f32) return *(const float4*)((const float*)p + i);
  ushort4 u = *(const ushort4*)((const unsigned short*)p + i);
  float4 r;
  r.x = bf2f(u.x); r.y = bf2f(u.y); r.z = bf2f(u.z); r.w = bf2f(u.w);
  return r;
}

__global__ __launch_bounds__(256) void detect_dtype(const float* q, int* flag) {
  __shared__ int cnt;
  if (threadIdx.x == 0) cnt = 0;
  __syncthreads();
  int c = 0;
  for (int i = threadIdx.x; i < 1024; i += 256) {
    unsigned u = __float_as_uint(q[i]);
    unsigned e = (u >> 23) & 0xffu;
    if (e >= 104u && e <= 140u) c++;
  }
  atomicAdd(&cnt, c);
  __syncthreads();
  if (threadIdx.x == 0) *flag = (cnt > 512) ? 1 : 0;
}

// ---------------------------------------------------------------------------
// 128x128-tile fp32 GEMM core, 8x8 per thread (quad-split), double-buffered.
// mode 0: Y[m][512] = X@W + bias        (normal row-major)
// mode 1: Kt[b][h][d][p] transposed head-major output (m = b*1024+p, n=h*64+d)
// ---------------------------------------------------------------------------
__device__ void gemm128(const void* __restrict__ X, const void* __restrict__ W,
                        const void* __restrict__ bias, float* __restrict__ Y,
                        const int bm, const int bn, const int mode,
                        const bool f32, float* lds) {
  const int tid = threadIdx.x;
  const int tx = tid & 15, ty = tid >> 4;
  const int lr = tid >> 1, lc = (tid & 1) * 8;   // A staging: row, col0
  const int wk = tid >> 5, wc = (tid & 31) * 4;  // B staging: k-row, col
  float acc[8][8] = {};
  float4 ra0, ra1, rb0, rb1;

  // prologue: tile 0 -> regs -> buf 0
  ra0 = ld4e(X, (size_t)(bm + lr) * 512 + lc, f32);
  ra1 = ld4e(X, (size_t)(bm + lr) * 512 + lc + 4, f32);
  rb0 = ld4e(W, (size_t)wk * 512 + bn + wc, f32);
  rb1 = ld4e(W, (size_t)(wk + 8) * 512 + bn + wc, f32);
  {
    float* Ab = lds;
    float* Bb = lds + 4096;
    Ab[(lc + 0) * 128 + lr] = ra0.x; Ab[(lc + 1) * 128 + lr] = ra0.y;
    Ab[(lc + 2) * 128 + lr] = ra0.z; Ab[(lc + 3) * 128 + lr] = ra0.w;
    Ab[(lc + 4) * 128 + lr] = ra1.x; Ab[(lc + 5) * 128 + lr] = ra1.y;
    Ab[(lc + 6) * 128 + lr] = ra1.z; Ab[(lc + 7) * 128 + lr] = ra1.w;
    *(float4*)&Bb[wk * 128 + wc] = rb0;
    *(float4*)&Bb[(wk + 8) * 128 + wc] = rb1;
  }
  __syncthreads();

  int buf = 0;
  for (int tt = 0; tt < 32; ++tt) {
    if (tt < 31) {  // issue next tile's global loads (overlap with compute)
      const int k0 = (tt + 1) * 16;
      ra0 = ld4e(X, (size_t)(bm + lr) * 512 + k0 + lc, f32);
      ra1 = ld4e(X, (size_t)(bm + lr) * 512 + k0 + lc + 4, f32);
      rb0 = ld4e(W, (size_t)(k0 + wk) * 512 + bn + wc, f32);
      rb1 = ld4e(W, (size_t)(k0 + wk + 8) * 512 + bn + wc, f32);
    }
    {
      const float* Ab = lds + buf * 2048;
      const float* Bb = lds + 4096 + buf * 2048;
#pragma unroll
      for (int k = 0; k < 16; ++k) {
        float4 aL = *(const float4*)&Ab[k * 128 + ty * 4];
        float4 aH = *(const float4*)&Ab[k * 128 + 64 + ty * 4];
        float4 bL = *(const float4*)&Bb[k * 128 + tx * 4];
        float4 bH = *(const float4*)&Bb[k * 128 + 64 + tx * 4];
        const float a8[8] = {aL.x, aL.y, aL.z, aL.w, aH.x, aH.y, aH.z, aH.w};
        const float b8[8] = {bL.x, bL.y, bL.z, bL.w, bH.x, bH.y, bH.z, bH.w};
#pragma unroll
        for (int i = 0; i < 8; ++i)
#pragma unroll
          for (int j = 0; j < 8; ++j)
            acc[i][j] = fmaf(a8[i], b8[j], acc[i][j]);
      }
    }
    if (tt < 31) {  // stage next tile into the other buffer
      float* Ab = lds + (buf ^ 1) * 2048;
      float* Bb = lds + 4096 + (buf ^ 1) * 2048;
      Ab[(lc + 0) * 128 + lr] = ra0.x; Ab[(lc + 1) * 128 + lr] = ra0.y;
      Ab[(lc + 2) * 128 + lr] = ra0.z; Ab[(lc + 3) * 128 + lr] = ra0.w;
      Ab[(lc + 4) * 128 + lr] = ra1.x; Ab[(lc + 5) * 128 + lr] = ra1.y;
      Ab[(lc + 6) * 128 + lr] = ra1.z; Ab[(lc + 7) * 128 + lr] = ra1.w;
      *(float4*)&Bb[wk * 128 + wc] = rb0;
      *(float4*)&Bb[(wk + 8) * 128 + wc] = rb1;
    }
    __syncthreads();
    buf ^= 1;
  }

  if (mode == 0) {
#pragma unroll
    for (int rh = 0; rh < 2; ++rh)
#pragma unroll
      for (int i = 0; i < 4; ++i) {
        const int r = bm + rh * 64 + ty * 4 + i;
#pragma unroll
        for (int ch = 0; ch < 2; ++ch) {
          const int c = bn + ch * 64 + tx * 4;
          float4 o;
          o.x = acc[rh * 4 + i][ch * 4 + 0] + ldf(bias, c + 0, f32);
          o.y = acc[rh * 4 + i][ch * 4 + 1] + ldf(bias, c + 1, f32);
          o.z = acc[rh * 4 + i][ch * 4 + 2] + ldf(bias, c + 2, f32);
          o.w = acc[rh * 4 + i][ch * 4 + 3] + ldf(bias, c + 3, f32);
          *(float4*)&Y[(size_t)r * 512 + c] = o;
        }
      }
  } else {
    const int bq = bm >> 10;
    const int pb = bm & 1023;
#pragma unroll
    for (int ch = 0; ch < 2; ++ch)
#pragma unroll
      for (int j = 0; j < 4; ++j) {
        const int c = bn + ch * 64 + tx * 4 + j;  // h = c>>6, d = c&63
        const float bb = ldf(bias, c, f32);
#pragma unroll
        for (int rh = 0; rh < 2; ++rh) {
          float4 pv;
          pv.x = acc[rh * 4 + 0][ch * 4 + j] + bb;
          pv.y = acc[rh * 4 + 1][ch * 4 + j] + bb;
          pv.z = acc[rh * 4 + 2][ch * 4 + j] + bb;
          pv.w = acc[rh * 4 + 3][ch * 4 + j] + bb;
          const int p0 = pb + rh * 64 + ty * 4;
          *(float4*)&Y[(((size_t)bq * 8 + (c >> 6)) * 64 + (c & 63)) * 1024 +
                       p0] = pv;
        }
      }
  }
}

// ---------------------------------------------------------------------------
// Q/K/V projections only (rbf lives inside attention).
// blocks 0..31:   Q-proj  (M=1024, mode 0)
// blocks 32..159: K-proj  (M=4096, mode 1 -> Kt[b][h][d][p])
// blocks 160..287:V-proj  (M=4096, mode 0)
// ---------------------------------------------------------------------------
__global__ __launch_bounds__(256) void qkv_gemm(
    const void* __restrict__ query, const void* __restrict__ key,
    const void* __restrict__ value, const void* __restrict__ Wq,
    const void* __restrict__ bq_, const void* __restrict__ Wk,
    const void* __restrict__ bk_, const void* __restrict__ Wv,
    const void* __restrict__ bv_, float* __restrict__ Qw,
    float* __restrict__ Ktw, float* __restrict__ Vw,
    const int* __restrict__ flag) {
  __shared__ float lds[8192];  // 32 KB double buffers
  const bool f32 = (*flag != 0);
  const int blk = blockIdx.x;

  const void *X, *W, *bias;
  float* Y;
  int mode, mi, ni;
  if (blk < 32) {
    X = query; W = Wq; bias = bq_; Y = Qw; mode = 0;
    mi = blk >> 2; ni = blk & 3;
  } else if (blk < 160) {
    const int q2 = blk - 32;
    X = key; W = Wk; bias = bk_; Y = Ktw; mode = 1;
    mi = q2 >> 2; ni = q2 & 3;
  } else {
    const int q2 = blk - 160;
    X = value; W = Wv; bias = bv_; Y = Vw; mode = 0;
    mi = q2 >> 2; ni = q2 & 3;
  }
  gemm128(X, W, bias, Y, mi * 128, ni * 128, mode, f32, lds);
}

// ---------------------------------------------------------------------------
// Attention v8: 2 queries/block, 512 threads. rbf bias computed IN-KERNEL
// (phase A) directly into scoresS. SPILL FIX vs v7: outer e-loop (4 rows,
// fully unrolled -> acc[e][h] static) x inner 25x float2 at unroll 2 ->
// ~80 live VGPRs, no scratch. rbf loads are nontemporal (protect Kt/V L2);
// scalar-float nontemporal builtins (struct float2 is not legal for the
// builtin on all ROCm versions).
// ---------------------------------------------------------------------------
#define SST 1028  // padded score stride

__global__ __launch_bounds__(512) void attn_v8(
    const float* __restrict__ Q,     // [B*L, 512]
    const float* __restrict__ Kt,    // [B][8][64][1024]
    const float* __restrict__ V,     // [B*P, 512]
    const void* __restrict__ rbf,    // [B*L*P, 50]
    const void* __restrict__ Wr,     // [50, 8]
    const void* __restrict__ br_,    // [8]
    const int* __restrict__ mask,    // [B,P]
    float* __restrict__ AO,          // [B*L, 512]
    void* __restrict__ d_out, const int* __restrict__ flag) {
  const int xcd = blockIdx.x & 7;
  const int idx = blockIdx.x >> 3;          // 0..63
  const int b = xcd >> 1;
  const int lp = ((xcd & 1) << 6) | idx;    // 0..127
  const int bl0 = b * LL + lp * 2;          // first of 2 queries
  const int t = threadIdx.x;
  const bool f32 = (*flag != 0);

  __shared__ float qS[2][512];              // 4 KB
  __shared__ float wrS[NRBF * 8];           // 1.6 KB
  __shared__ float brS[8];
  __shared__ float scoresS[2][8 * SST];     // 65.8 KB

  for (int i = t; i < 1024; i += 512)
    qS[i >> 9][i & 511] = Q[(size_t)bl0 * 512 + i];
  for (int i = t; i < NRBF * 8; i += 512) wrS[i] = ldf(Wr, i, f32);
  if (t < 8) brS[t] = ldf(br_, t, f32);
  __syncthreads();

  // ---- phase A: rbf bias -> scoresS (initializer) ----
  {
    const int q = t >> 8;        // which query
    const int tq = t & 255;      // p-quad
    float acc[4][8];
#pragma unroll
    for (int e = 0; e < 4; ++e)
#pragma unroll
      for (int h = 0; h < 8; ++h) acc[e][h] = brS[h];
    const size_t rbase = ((size_t)(bl0 + q) * 1024 + 4 * tq) * NRBF;
    if (f32) {
      const float* rowb = (const float*)rbf + rbase;
#pragma unroll
      for (int e = 0; e < 4; ++e) {
        const float* rp = rowb + e * NRBF;
#pragma unroll 2
        for (int j = 0; j < 25; ++j) {
          const float rx = __builtin_nontemporal_load(rp + 2 * j);
          const float ry = __builtin_nontemporal_load(rp + 2 * j + 1);
          const float4 wa = *(const float4*)&wrS[(2 * j) * 8];
          const float4 wb = *(const float4*)&wrS[(2 * j) * 8 + 4];
          const float4 wc = *(const float4*)&wrS[(2 * j + 1) * 8];
          const float4 wd = *(const float4*)&wrS[(2 * j + 1) * 8 + 4];
          acc[e][0] = fmaf(rx, wa.x, acc[e][0]);
          acc[e][1] = fmaf(rx, wa.y, acc[e][1]);
          acc[e][2] = fmaf(rx, wa.z, acc[e][2]);
          acc[e][3] = fmaf(rx, wa.w, acc[e][3]);
          acc[e][4] = fmaf(rx, wb.x, acc[e][4]);
          acc[e][5] = fmaf(rx, wb.y, acc[e][5]);
          acc[e][6] = fmaf(rx, wb.z, acc[e][6]);
          acc[e][7] = fmaf(rx, wb.w, acc[e][7]);
          acc[e][0] = fmaf(ry, wc.x, acc[e][0]);
          acc[e][1] = fmaf(ry, wc.y, acc[e][1]);
          acc[e][2] = fmaf(ry, wc.z, acc[e][2]);
          acc[e][3] = fmaf(ry, wc.w, acc[e][3]);
          acc[e][4] = fmaf(ry, wd.x, acc[e][4]);
          acc[e][5] = fmaf(ry, wd.y, acc[e][5]);
          acc[e][6] = fmaf(ry, wd.z, acc[e][6]);
          acc[e][7] = fmaf(ry, wd.w, acc[e][7]);
        }
      }
    } else {
      const unsigned short* rb = (const unsigned short*)rbf + rbase;
#pragma unroll
      for (int e = 0; e < 4; ++e) {
#pragma unroll 1
        for (int j = 0; j < 50; ++j) {
          const float rv = bf2f(rb[e * 50 + j]);
#pragma unroll
          for (int h = 0; h < 8; ++h)
            acc[e][h] = fmaf(rv, wrS[j * 8 + h], acc[e][h]);
        }
      }
    }
#pragma unroll
    for (int h = 0; h < 8; ++h) {
      float4 o;
      o.x = acc[0][h]; o.y = acc[1][h]; o.z = acc[2][h]; o.w = acc[3][h];
      *(float4*)&scoresS[q][h * SST + 4 * tq] = o;  // lane-consecutive
    }
  }
  __syncthreads();

  // ---- phase B: scores = bias + 0.125*QK^T (bias read from LDS) ----
  {
    const int tq = t & 255;
    const int hh = t >> 8;
    const int4 mk4 = *(const int4*)(mask + b * PP + 4 * tq);
#pragma unroll 1
    for (int hi = 0; hi < 4; ++hi) {
      const int h = hh * 4 + hi;
      const float4* ktp =
          (const float4*)(Kt + ((size_t)b * 8 + h) * 64 * 1024) + tq;
      float4 a0 = {0.f, 0.f, 0.f, 0.f}, a1 = {0.f, 0.f, 0.f, 0.f};
#pragma unroll 2
      for (int dq = 0; dq < 16; ++dq) {
        float4 qa = *(const float4*)&qS[0][h * 64 + dq * 4];  // bcast
        float4 qb = *(const float4*)&qS[1][h * 64 + dq * 4];
        float4 k0 = ktp[(size_t)(dq * 4 + 0) * 256];
        float4 k1 = ktp[(size_t)(dq * 4 + 1) * 256];
        float4 k2 = ktp[(size_t)(dq * 4 + 2) * 256];
        float4 k3 = ktp[(size_t)(dq * 4 + 3) * 256];
        a0.x = fmaf(qa.x, k0.x, a0.x); a0.y = fmaf(qa.x, k0.y, a0.y);
        a0.z = fmaf(qa.x, k0.z, a0.z); a0.w = fmaf(qa.x, k0.w, a0.w);
        a0.x = fmaf(qa.y, k1.x, a0.x); a0.y = fmaf(qa.y, k1.y, a0.y);
        a0.z = fmaf(qa.y, k1.z, a0.z); a0.w = fmaf(qa.y, k1.w, a0.w);
        a0.x = fmaf(qa.z, k2.x, a0.x); a0.y = fmaf(qa.z, k2.y, a0.y);
        a0.z = fmaf(qa.z, k2.z, a0.z); a0.w = fmaf(qa.z, k2.w, a0.w);
        a0.x = fmaf(qa.w, k3.x, a0.x); a0.y = fmaf(qa.w, k3.y, a0.y);
        a0.z = fmaf(qa.w, k3.z, a0.z); a0.w = fmaf(qa.w, k3.w, a0.w);
        a1.x = fmaf(qb.x, k0.x, a1.x); a1.y = fmaf(qb.x, k0.y, a1.y);
        a1.z = fmaf(qb.x, k0.z, a1.z); a1.w = fmaf(qb.x, k0.w, a1.w);
        a1.x = fmaf(qb.y, k1.x, a1.x); a1.y = fmaf(qb.y, k1.y, a1.y);
        a1.z = fmaf(qb.y, k1.z, a1.z); a1.w = fmaf(qb.y, k1.w, a1.w);
        a1.x = fmaf(qb.z, k2.x, a1.x); a1.y = fmaf(qb.z, k2.y, a1.y);
        a1.z = fmaf(qb.z, k2.z, a1.z); a1.w = fmaf(qb.z, k2.w, a1.w);
        a1.x = fmaf(qb.w, k3.x, a1.x); a1.y = fmaf(qb.w, k3.y, a1.y);
        a1.z = fmaf(qb.w, k3.z, a1.z); a1.w = fmaf(qb.w, k3.w, a1.w);
      }
      float4 b40 = *(const float4*)&scoresS[0][h * SST + 4 * tq];
      float4 b41 = *(const float4*)&scoresS[1][h * SST + 4 * tq];
      float4 s0, s1;
      s0.x = (mk4.x == 0) ? -1e9f : fmaf(a0.x, 0.125f, b40.x);
      s0.y = (mk4.y == 0) ? -1e9f : fmaf(a0.y, 0.125f, b40.y);
      s0.z = (mk4.z == 0) ? -1e9f : fmaf(a0.z, 0.125f, b40.z);
      s0.w = (mk4.w == 0) ? -1e9f : fmaf(a0.w, 0.125f, b40.w);
      s1.x = (mk4.x == 0) ? -1e9f : fmaf(a1.x, 0.125f, b41.x);
      s1.y = (mk4.y == 0) ? -1e9f : fmaf(a1.y, 0.125f, b41.y);
      s1.z = (mk4.z == 0) ? -1e9f : fmaf(a1.z, 0.125f, b41.z);
      s1.w = (mk4.w == 0) ? -1e9f : fmaf(a1.w, 0.125f, b41.w);
      *(float4*)&scoresS[0][h * SST + 4 * tq] = s0;
      *(float4*)&scoresS[1][h * SST + 4 * tq] = s1;
    }
  }
  __syncthreads();

  // ---- softmax over P: 16 (q,h) rows, 2 per wave ----
  {
    const int wave = t >> 6, lane = t & 63;
    for (int pr = wave * 2; pr < wave * 2 + 2; ++pr) {
      float* sc = &scoresS[pr >> 3][(pr & 7) * SST];
      float m = -3.0e38f;
      for (int i = lane; i < PP; i += 64) m = fmaxf(m, sc[i]);
#pragma unroll
      for (int off = 32; off; off >>= 1) m = fmaxf(m, __shfl_xor(m, off, 64));
      float sum = 0.f;
      for (int i = lane; i < PP; i += 64) {
        float e = __expf(sc[i] - m);
        sc[i] = e;
        sum += e;
      }
#pragma unroll
      for (int off = 32; off; off >>= 1) sum += __shfl_xor(sum, off, 64);
      const float inv = 1.0f / sum;
      for (int i = lane; i < PP; i += 64) sc[i] *= inv;
    }
  }
  __syncthreads();

  // ---- attn_mean: q = t>>8, p-quad = t&255 ----
  {
    const int q = t >> 8, pq = t & 255;
    float4 s = {0.f, 0.f, 0.f, 0.f};
#pragma unroll
    for (int h = 0; h < 8; ++h) {
      float4 v = *(const float4*)&scoresS[q][h * SST + 4 * pq];
      s.x += v.x; s.y += v.y; s.z += v.z; s.w += v.w;
    }
    s.x *= 0.125f; s.y *= 0.125f; s.z *= 0.125f; s.w *= 0.125f;
    const size_t base =
        (size_t)BB * LL * DD + (size_t)(bl0 + q) * PP + 4 * pq;
    if (f32) {
      *(float4*)((float*)d_out + base) = s;
    } else {
      __hip_bfloat16* o1 = (__hip_bfloat16*)d_out;
      o1[base + 0] = __float2bfloat16(s.x);
      o1[base + 1] = __float2bfloat16(s.y);
      o1[base + 2] = __float2bfloat16(s.z);
      o1[base + 3] = __float2bfloat16(s.w);
    }
  }

  // ---- PV: thread owns c-quad (cq) and p-quarter (ph); both queries ----
  float4 pa0, pa1;
  {
    const int cq = t & 127;
    const int ph = t >> 7;  // 0..3, 256 p each
    const int h = cq >> 4;
    const float* sc0 = &scoresS[0][h * SST];
    const float* sc1 = &scoresS[1][h * SST];
    const float4* Vb = (const float4*)(V + (size_t)b * PP * 512) + cq;
    float4 A0 = {0.f, 0.f, 0.f, 0.f}, A1 = {0.f, 0.f, 0.f, 0.f};
    const int p0 = ph * 256;
#pragma unroll 2
    for (int p4 = p0; p4 < p0 + 256; p4 += 4) {
      float4 pr0 = *(const float4*)&sc0[p4];
      float4 pr1 = *(const float4*)&sc1[p4];
      float4 v0 = Vb[(size_t)(p4 + 0) * 128];
      float4 v1 = Vb[(size_t)(p4 + 1) * 128];
      float4 v2 = Vb[(size_t)(p4 + 2) * 128];
      float4 v3 = Vb[(size_t)(p4 + 3) * 128];
      A0.x = fmaf(pr0.x, v0.x, A0.x); A0.y = fmaf(pr0.x, v0.y, A0.y);
      A0.z = fmaf(pr0.x, v0.z, A0.z); A0.w = fmaf(pr0.x, v0.w, A0.w);
      A0.x = fmaf(pr0.y, v1.x, A0.x); A0.y = fmaf(pr0.y, v1.y, A0.y);
      A0.z = fmaf(pr0.y, v1.z, A0.z); A0.w = fmaf(pr0.y, v1.w, A0.w);
      A0.x = fmaf(pr0.z, v2.x, A0.x); A0.y = fmaf(pr0.z, v2.y, A0.y);
      A0.z = fmaf(pr0.z, v2.z, A0.z); A0.w = fmaf(pr0.z, v2.w, A0.w);
      A0.x = fmaf(pr0.w, v3.x, A0.x); A0.y = fmaf(pr0.w, v3.y, A0.y);
      A0.z = fmaf(pr0.w, v3.z, A0.z); A0.w = fmaf(pr0.w, v3.w, A0.w);
      A1.x = fmaf(pr1.x, v0.x, A1.x); A1.y = fmaf(pr1.x, v0.y, A1.y);
      A1.z = fmaf(pr1.x, v0.z, A1.z); A1.w = fmaf(pr1.x, v0.w, A1.w);
      A1.x = fmaf(pr1.y, v1.x, A1.x); A1.y = fmaf(pr1.y, v1.y, A1.y);
      A1.z = fmaf(pr1.y, v1.z, A1.z); A1.w = fmaf(pr1.y, v1.w, A1.w);
      A1.x = fmaf(pr1.z, v2.x, A1.x); A1.y = fmaf(pr1.z, v2.y, A1.y);
      A1.z = fmaf(pr1.z, v2.z, A1.z); A1.w = fmaf(pr1.z, v2.w, A1.w);
      A1.x = fmaf(pr1.w, v3.x, A1.x); A1.y = fmaf(pr1.w, v3.y, A1.y);
      A1.z = fmaf(pr1.w, v3.z, A1.z); A1.w = fmaf(pr1.w, v3.w, A1.w);
    }
    pa0 = A0;
    pa1 = A1;
  }
  __syncthreads();  // all score reads complete; safe to reuse LDS
  {
    const int cq = t & 127, ph = t >> 7;
    float* parts = &scoresS[0][0];  // [2 q][4 ph][128 cq][4] = 16 KB alias
    *(float4*)&parts[((0 * 4 + ph) * 128 + cq) * 4] = pa0;
    *(float4*)&parts[((1 * 4 + ph) * 128 + cq) * 4] = pa1;
  }
  __syncthreads();
  if (t < 256) {
    const int q = t >> 7, c = t & 127;
    const float* parts = &scoresS[0][0];
    float4 a = *(const float4*)&parts[((q * 4 + 0) * 128 + c) * 4];
#pragma unroll
    for (int ph = 1; ph < 4; ++ph) {
      float4 x = *(const float4*)&parts[((q * 4 + ph) * 128 + c) * 4];
      a.x += x.x; a.y += x.y; a.z += x.z; a.w += x.w;
    }
    *(float4*)&AO[(size_t)(bl0 + q) * 512 + 4 * c] = a;
  }
}

// ---------------------------------------------------------------------------
// Output projection + residual: Xout = AO@Wo + bo + query   (fp32 ws)
// ---------------------------------------------------------------------------
__global__ __launch_bounds__(256) void proj_out(
    const float* __restrict__ X, const void* __restrict__ W,
    const void* __restrict__ bias, const void* __restrict__ resid,
    float* __restrict__ Y, const int* __restrict__ flag) {
  __shared__ float As[16][64];
  __shared__ float Bs[16][64];
  const bool f32 = (*flag != 0);
  const int bm = blockIdx.x * 64, bn = blockIdx.y * 64;
  const int tid = threadIdx.x;
  const int tx = tid & 15, ty = tid >> 4;
  float acc[4][4] = {};
  for (int k0 = 0; k0 < 512; k0 += 16) {
    {
      int r = tid >> 2, kf = (tid & 3) * 4;
      float4 x4 = *(const float4*)(X + (size_t)(bm + r) * 512 + k0 + kf);
      As[kf + 0][r] = x4.x; As[kf + 1][r] = x4.y;
      As[kf + 2][r] = x4.z; As[kf + 3][r] = x4.w;
    }
    if (f32) {
      int kk = tid >> 4, cf = (tid & 15) * 4;
      *(float4*)&Bs[kk][cf] =
          *(const float4*)((const float*)W + (size_t)(k0 + kk) * 512 + bn + cf);
    } else {
      const unsigned short* Wb = (const unsigned short*)W;
      for (int f = tid; f < 16 * 64; f += 256) {
        int kk = f >> 6, c = f & 63;
        Bs[kk][c] = bf2f(Wb[(size_t)(k0 + kk) * 512 + bn + c]);
      }
    }
    __syncthreads();
#pragma unroll
    for (int k = 0; k < 16; ++k) {
      float4 a4 = *(const float4*)&As[k][ty * 4];
      float4 b4 = *(const float4*)&Bs[k][tx * 4];
      acc[0][0] = fmaf(a4.x, b4.x, acc[0][0]); acc[0][1] = fmaf(a4.x, b4.y, acc[0][1]);
      acc[0][2] = fmaf(a4.x, b4.z, acc[0][2]); acc[0][3] = fmaf(a4.x, b4.w, acc[0][3]);
      acc[1][0] = fmaf(a4.y, b4.x, acc[1][0]); acc[1][1] = fmaf(a4.y, b4.y, acc[1][1]);
      acc[1][2] = fmaf(a4.y, b4.z, acc[1][2]); acc[1][3] = fmaf(a4.y, b4.w, acc[1][3]);
      acc[2][0] = fmaf(a4.z, b4.x, acc[2][0]); acc[2][1] = fmaf(a4.z, b4.y, acc[2][1]);
      acc[2][2] = fmaf(a4.z, b4.z, acc[2][2]); acc[2][3] = fmaf(a4.z, b4.w, acc[2][3]);
      acc[3][0] = fmaf(a4.w, b4.x, acc[3][0]); acc[3][1] = fmaf(a4.w, b4.y, acc[3][1]);
      acc[3][2] = fmaf(a4.w, b4.z, acc[3][2]); acc[3][3] = fmaf(a4.w, b4.w, acc[3][3]);
    }
    __syncthreads();
  }
#pragma unroll
  for (int i = 0; i < 4; ++i) {
    int r = bm + ty * 4 + i;
    float4 o;
#pragma unroll
    for (int j = 0; j < 4; ++j) {
      int c = bn + tx * 4 + j;
      float v = acc[i][j] + ldf(bias, c, f32) +
                ldf(resid, (size_t)r * 512 + c, f32);
      ((float*)&o)[j] = v;
    }
    *(float4*)(Y + (size_t)r * 512 + bn + tx * 4) = o;
  }
}

// ---------------------------------------------------------------------------
// LayerNorm rows of Xw -> out0
// ---------------------------------------------------------------------------
__global__ __launch_bounds__(256) void ln_kernel(
    const float* __restrict__ Xw, const void* __restrict__ gamma,
    const void* __restrict__ beta, void* __restrict__ d_out,
    const int* __restrict__ flag) {
  const int bl = blockIdx.x;
  const int tid = threadIdx.x;
  const bool f32 = (*flag != 0);
  __shared__ float red[16];
  float v0 = Xw[(size_t)bl * 512 + tid];
  float v1 = Xw[(size_t)bl * 512 + tid + 256];
  float s = v0 + v1, s2 = v0 * v0 + v1 * v1;
#pragma unroll
  for (int off = 32; off; off >>= 1) {
    s += __shfl_xor(s, off, 64);
    s2 += __shfl_xor(s2, off, 64);
  }
  const int wave = tid >> 6, lane = tid & 63;
  if (lane == 0) { red[wave] = s; red[8 + wave] = s2; }
  __syncthreads();
  if (tid == 0) {
    float ts = 0.f, ts2 = 0.f;
    for (int w = 0; w < 4; ++w) { ts += red[w]; ts2 += red[8 + w]; }
    red[0] = ts; red[1] = ts2;
  }
  __syncthreads();
  const float mu = red[0] * (1.0f / 512.0f);
  const float var = red[1] * (1.0f / 512.0f) - mu * mu;
  const float rstd = rsqrtf(var + 1e-5f);
  float o0 = (v0 - mu) * rstd * ldf(gamma, tid, f32) + ldf(beta, tid, f32);
  float o1 = (v1 - mu) * rstd * ldf(gamma, tid + 256, f32) +
             ldf(beta, tid + 256, f32);
  if (f32) {
    float* o = (float*)d_out;
    o[(size_t)bl * 512 + tid] = o0;
    o[(size_t)bl * 512 + tid + 256] = o1;
  } else {
    __hip_bfloat16* o = (__hip_bfloat16*)d_out;
    o[(size_t)bl * 512 + tid] = __float2bfloat16(o0);
    o[(size_t)bl * 512 + tid + 256] = __float2bfloat16(o1);
  }
}

// ---------------------------------------------------------------------------
extern "C" void kernel_launch(void* const* d_in, const int* in_sizes, int n_in,
                              void* d_out, int out_size, void* d_ws,
                              size_t ws_size, hipStream_t stream) {
  const void* query = d_in[0];
  const void* key = d_in[1];
  const void* value = d_in[2];
  const void* rbf = d_in[3];
  const int* key_mask = (const int*)d_in[4];
  const void* Wq = d_in[5];
  const void* bq = d_in[6];
  const void* Wk = d_in[7];
  const void* bk = d_in[8];
  const void* Wv = d_in[9];
  const void* bv = d_in[10];
  const void* Wr = d_in[11];
  const void* br = d_in[12];
  const void* Wo = d_in[13];
  const void* bo = d_in[14];
  const void* gamma = d_in[15];
  const void* beta = d_in[16];

  // ws: [flag 16B] Q | Kt | V | AO | X
  int* flag = (int*)d_ws;
  float* base = (float*)d_ws + 4;
  float* Qw = base;
  float* Ktw = Qw + (size_t)BB * LL * DD;   // +524288
  float* Vw = Ktw + (size_t)BB * PP * DD;   // +2097152
  float* AO = Vw + (size_t)BB * PP * DD;    // +2097152
  float* Xw = AO + (size_t)BB * LL * DD;    // +524288

  detect_dtype<<<1, 256, 0, stream>>>((const float*)query, flag);
  qkv_gemm<<<dim3(288), 256, 0, stream>>>(query, key, value, Wq, bq, Wk, bk,
                                          Wv, bv, Qw, Ktw, Vw, flag);
  attn_v8<<<dim3(BB * LL / 2), 512, 0, stream>>>(Qw, Ktw, Vw, rbf, Wr, br,
                                                 key_mask, AO, d_out, flag);
  proj_out<<<dim3(16, 8), 256, 0, stream>>>(AO, Wo, bo, query, Xw, flag);
  ln_kernel<<<dim3(BB * LL), 256, 0, stream>>>(Xw, gamma, beta, d_out, flag);
}

// Round 6
// 743.366 us; speedup vs baseline: 1.2995x; 1.2995x over previous
//
#include <hip/hip_runtime.h>
#include <hip/hip_bf16.h>

#define BB 4
#define LL 256
#define PP 1024
#define DD 512
#define HH 8
#define HD 64
#define NRBF 50

// ---------------------------------------------------------------------------
// dtype helpers (inputs are fp32 per reference; bf16 fallback kept for safety)
// ---------------------------------------------------------------------------
__device__ __forceinline__ float bf2f(unsigned short u) {
  return __uint_as_float((unsigned)u << 16);
}

__device__ __forceinline__ float ldf(const void* p, size_t i, bool f32) {
  if (f32) return ((const float*)p)[i];
  return bf2f(((const unsigned short*)p)[i]);
}

__device__ __forceinline__ float4 ld4e(const void* p, size_t i, bool f32) {
  if (f32) return *(const float4*)((const float*)p + i);
  ushort4 u = *(const ushort4*)((const unsigned short*)p + i);
  float4 r;
  r.x = bf2f(u.x); r.y = bf2f(u.y); r.z = bf2f(u.z); r.w = bf2f(u.w);
  return r;
}

__global__ __launch_bounds__(256) void detect_dtype(const float* q, int* flag) {
  __shared__ int cnt;
  if (threadIdx.x == 0) cnt = 0;
  __syncthreads();
  int c = 0;
  for (int i = threadIdx.x; i < 1024; i += 256) {
    unsigned u = __float_as_uint(q[i]);
    unsigned e = (u >> 23) & 0xffu;
    if (e >= 104u && e <= 140u) c++;
  }
  atomicAdd(&cnt, c);
  __syncthreads();
  if (threadIdx.x == 0) *flag = (cnt > 512) ? 1 : 0;
}

// ---------------------------------------------------------------------------
// 128x128-tile fp32 GEMM core, 8x8 per thread (quad-split), double-buffered.
// mode 0: Y[m][512] = X@W + bias        (normal row-major)
// mode 1: Kt[b][h][d][p] transposed head-major output (m = b*1024+p, n=h*64+d)
// ---------------------------------------------------------------------------
__device__ void gemm128(const void* __restrict__ X, const void* __restrict__ W,
                        const void* __restrict__ bias, float* __restrict__ Y,
                        const int bm, const int bn, const int mode,
                        const bool f32, float* lds) {
  const int tid = threadIdx.x;
  const int tx = tid & 15, ty = tid >> 4;
  const int lr = tid >> 1, lc = (tid & 1) * 8;   // A staging: row, col0
  const int wk = tid >> 5, wc = (tid & 31) * 4;  // B staging: k-row, col
  float acc[8][8] = {};
  float4 ra0, ra1, rb0, rb1;

  // prologue: tile 0 -> regs -> buf 0
  ra0 = ld4e(X, (size_t)(bm + lr) * 512 + lc, f32);
  ra1 = ld4e(X, (size_t)(bm + lr) * 512 + lc + 4, f32);
  rb0 = ld4e(W, (size_t)wk * 512 + bn + wc, f32);
  rb1 = ld4e(W, (size_t)(wk + 8) * 512 + bn + wc, f32);
  {
    float* Ab = lds;
    float* Bb = lds + 4096;
    Ab[(lc + 0) * 128 + lr] = ra0.x; Ab[(lc + 1) * 128 + lr] = ra0.y;
    Ab[(lc + 2) * 128 + lr] = ra0.z; Ab[(lc + 3) * 128 + lr] = ra0.w;
    Ab[(lc + 4) * 128 + lr] = ra1.x; Ab[(lc + 5) * 128 + lr] = ra1.y;
    Ab[(lc + 6) * 128 + lr] = ra1.z; Ab[(lc + 7) * 128 + lr] = ra1.w;
    *(float4*)&Bb[wk * 128 + wc] = rb0;
    *(float4*)&Bb[(wk + 8) * 128 + wc] = rb1;
  }
  __syncthreads();

  int buf = 0;
  for (int tt = 0; tt < 32; ++tt) {
    if (tt < 31) {  // issue next tile's global loads (overlap with compute)
      const int k0 = (tt + 1) * 16;
      ra0 = ld4e(X, (size_t)(bm + lr) * 512 + k0 + lc, f32);
      ra1 = ld4e(X, (size_t)(bm + lr) * 512 + k0 + lc + 4, f32);
      rb0 = ld4e(W, (size_t)(k0 + wk) * 512 + bn + wc, f32);
      rb1 = ld4e(W, (size_t)(k0 + wk + 8) * 512 + bn + wc, f32);
    }
    {
      const float* Ab = lds + buf * 2048;
      const float* Bb = lds + 4096 + buf * 2048;
#pragma unroll
      for (int k = 0; k < 16; ++k) {
        float4 aL = *(const float4*)&Ab[k * 128 + ty * 4];
        float4 aH = *(const float4*)&Ab[k * 128 + 64 + ty * 4];
        float4 bL = *(const float4*)&Bb[k * 128 + tx * 4];
        float4 bH = *(const float4*)&Bb[k * 128 + 64 + tx * 4];
        const float a8[8] = {aL.x, aL.y, aL.z, aL.w, aH.x, aH.y, aH.z, aH.w};
        const float b8[8] = {bL.x, bL.y, bL.z, bL.w, bH.x, bH.y, bH.z, bH.w};
#pragma unroll
        for (int i = 0; i < 8; ++i)
#pragma unroll
          for (int j = 0; j < 8; ++j)
            acc[i][j] = fmaf(a8[i], b8[j], acc[i][j]);
      }
    }
    if (tt < 31) {  // stage next tile into the other buffer
      float* Ab = lds + (buf ^ 1) * 2048;
      float* Bb = lds + 4096 + (buf ^ 1) * 2048;
      Ab[(lc + 0) * 128 + lr] = ra0.x; Ab[(lc + 1) * 128 + lr] = ra0.y;
      Ab[(lc + 2) * 128 + lr] = ra0.z; Ab[(lc + 3) * 128 + lr] = ra0.w;
      Ab[(lc + 4) * 128 + lr] = ra1.x; Ab[(lc + 5) * 128 + lr] = ra1.y;
      Ab[(lc + 6) * 128 + lr] = ra1.z; Ab[(lc + 7) * 128 + lr] = ra1.w;
      *(float4*)&Bb[wk * 128 + wc] = rb0;
      *(float4*)&Bb[(wk + 8) * 128 + wc] = rb1;
    }
    __syncthreads();
    buf ^= 1;
  }

  if (mode == 0) {
#pragma unroll
    for (int rh = 0; rh < 2; ++rh)
#pragma unroll
      for (int i = 0; i < 4; ++i) {
        const int r = bm + rh * 64 + ty * 4 + i;
#pragma unroll
        for (int ch = 0; ch < 2; ++ch) {
          const int c = bn + ch * 64 + tx * 4;
          float4 o;
          o.x = acc[rh * 4 + i][ch * 4 + 0] + ldf(bias, c + 0, f32);
          o.y = acc[rh * 4 + i][ch * 4 + 1] + ldf(bias, c + 1, f32);
          o.z = acc[rh * 4 + i][ch * 4 + 2] + ldf(bias, c + 2, f32);
          o.w = acc[rh * 4 + i][ch * 4 + 3] + ldf(bias, c + 3, f32);
          *(float4*)&Y[(size_t)r * 512 + c] = o;
        }
      }
  } else {
    const int bq = bm >> 10;
    const int pb = bm & 1023;
#pragma unroll
    for (int ch = 0; ch < 2; ++ch)
#pragma unroll
      for (int j = 0; j < 4; ++j) {
        const int c = bn + ch * 64 + tx * 4 + j;  // h = c>>6, d = c&63
        const float bb = ldf(bias, c, f32);
#pragma unroll
        for (int rh = 0; rh < 2; ++rh) {
          float4 pv;
          pv.x = acc[rh * 4 + 0][ch * 4 + j] + bb;
          pv.y = acc[rh * 4 + 1][ch * 4 + j] + bb;
          pv.z = acc[rh * 4 + 2][ch * 4 + j] + bb;
          pv.w = acc[rh * 4 + 3][ch * 4 + j] + bb;
          const int p0 = pb + rh * 64 + ty * 4;
          *(float4*)&Y[(((size_t)bq * 8 + (c >> 6)) * 64 + (c & 63)) * 1024 +
                       p0] = pv;
        }
      }
  }
}

// ---------------------------------------------------------------------------
// Q/K/V projections only (rbf lives inside attention).
// blocks 0..31:   Q-proj  (M=1024, mode 0)
// blocks 32..159: K-proj  (M=4096, mode 1 -> Kt[b][h][d][p])
// blocks 160..287:V-proj  (M=4096, mode 0)
// ---------------------------------------------------------------------------
__global__ __launch_bounds__(256) void qkv_gemm(
    const void* __restrict__ query, const void* __restrict__ key,
    const void* __restrict__ value, const void* __restrict__ Wq,
    const void* __restrict__ bq_, const void* __restrict__ Wk,
    const void* __restrict__ bk_, const void* __restrict__ Wv,
    const void* __restrict__ bv_, float* __restrict__ Qw,
    float* __restrict__ Ktw, float* __restrict__ Vw,
    const int* __restrict__ flag) {
  __shared__ float lds[8192];  // 32 KB double buffers
  const bool f32 = (*flag != 0);
  const int blk = blockIdx.x;

  const void *X, *W, *bias;
  float* Y;
  int mode, mi, ni;
  if (blk < 32) {
    X = query; W = Wq; bias = bq_; Y = Qw; mode = 0;
    mi = blk >> 2; ni = blk & 3;
  } else if (blk < 160) {
    const int q2 = blk - 32;
    X = key; W = Wk; bias = bk_; Y = Ktw; mode = 1;
    mi = q2 >> 2; ni = q2 & 3;
  } else {
    const int q2 = blk - 160;
    X = value; W = Wv; bias = bv_; Y = Vw; mode = 0;
    mi = q2 >> 2; ni = q2 & 3;
  }
  gemm128(X, W, bias, Y, mi * 128, ni * 128, mode, f32, lds);
}

// ---------------------------------------------------------------------------
// Attention v9: identical to v8 except phase A uses plain cached float2
// loads (NO nontemporal). v8's nt hint caused 6x HBM re-fetch of the rbf
// stream (FETCH 1.31 GB): nt drops the line after each 4-B scalar load, so
// the remaining 49 loads of the same 200-B row re-fetch from HBM. Cached
// float2 walk -> each line fetched once, fully consumed.
// ---------------------------------------------------------------------------
#define SST 1028  // padded score stride

__global__ __launch_bounds__(512) void attn_v9(
    const float* __restrict__ Q,     // [B*L, 512]
    const float* __restrict__ Kt,    // [B][8][64][1024]
    const float* __restrict__ V,     // [B*P, 512]
    const void* __restrict__ rbf,    // [B*L*P, 50]
    const void* __restrict__ Wr,     // [50, 8]
    const void* __restrict__ br_,    // [8]
    const int* __restrict__ mask,    // [B,P]
    float* __restrict__ AO,          // [B*L, 512]
    void* __restrict__ d_out, const int* __restrict__ flag) {
  const int xcd = blockIdx.x & 7;
  const int idx = blockIdx.x >> 3;          // 0..63
  const int b = xcd >> 1;
  const int lp = ((xcd & 1) << 6) | idx;    // 0..127
  const int bl0 = b * LL + lp * 2;          // first of 2 queries
  const int t = threadIdx.x;
  const bool f32 = (*flag != 0);

  __shared__ float qS[2][512];              // 4 KB
  __shared__ float wrS[NRBF * 8];           // 1.6 KB
  __shared__ float brS[8];
  __shared__ float scoresS[2][8 * SST];     // 65.8 KB

  for (int i = t; i < 1024; i += 512)
    qS[i >> 9][i & 511] = Q[(size_t)bl0 * 512 + i];
  for (int i = t; i < NRBF * 8; i += 512) wrS[i] = ldf(Wr, i, f32);
  if (t < 8) brS[t] = ldf(br_, t, f32);
  __syncthreads();

  // ---- phase A: rbf bias -> scoresS (initializer) ----
  {
    const int q = t >> 8;        // which query
    const int tq = t & 255;      // p-quad
    float acc[4][8];
#pragma unroll
    for (int e = 0; e < 4; ++e)
#pragma unroll
      for (int h = 0; h < 8; ++h) acc[e][h] = brS[h];
    const size_t rbase = ((size_t)(bl0 + q) * 1024 + 4 * tq) * NRBF;
    if (f32) {
      const float* rowb = (const float*)rbf + rbase;
#pragma unroll
      for (int e = 0; e < 4; ++e) {
        const float2* rp = (const float2*)(rowb + e * NRBF);  // 8-B aligned
#pragma unroll 2
        for (int j = 0; j < 25; ++j) {
          const float2 r2 = rp[j];
          const float4 wa = *(const float4*)&wrS[(2 * j) * 8];
          const float4 wb = *(const float4*)&wrS[(2 * j) * 8 + 4];
          const float4 wc = *(const float4*)&wrS[(2 * j + 1) * 8];
          const float4 wd = *(const float4*)&wrS[(2 * j + 1) * 8 + 4];
          acc[e][0] = fmaf(r2.x, wa.x, acc[e][0]);
          acc[e][1] = fmaf(r2.x, wa.y, acc[e][1]);
          acc[e][2] = fmaf(r2.x, wa.z, acc[e][2]);
          acc[e][3] = fmaf(r2.x, wa.w, acc[e][3]);
          acc[e][4] = fmaf(r2.x, wb.x, acc[e][4]);
          acc[e][5] = fmaf(r2.x, wb.y, acc[e][5]);
          acc[e][6] = fmaf(r2.x, wb.z, acc[e][6]);
          acc[e][7] = fmaf(r2.x, wb.w, acc[e][7]);
          acc[e][0] = fmaf(r2.y, wc.x, acc[e][0]);
          acc[e][1] = fmaf(r2.y, wc.y, acc[e][1]);
          acc[e][2] = fmaf(r2.y, wc.z, acc[e][2]);
          acc[e][3] = fmaf(r2.y, wc.w, acc[e][3]);
          acc[e][4] = fmaf(r2.y, wd.x, acc[e][4]);
          acc[e][5] = fmaf(r2.y, wd.y, acc[e][5]);
          acc[e][6] = fmaf(r2.y, wd.z, acc[e][6]);
          acc[e][7] = fmaf(r2.y, wd.w, acc[e][7]);
        }
      }
    } else {
      const unsigned short* rb = (const unsigned short*)rbf + rbase;
#pragma unroll
      for (int e = 0; e < 4; ++e) {
#pragma unroll 1
        for (int j = 0; j < 50; ++j) {
          const float rv = bf2f(rb[e * 50 + j]);
#pragma unroll
          for (int h = 0; h < 8; ++h)
            acc[e][h] = fmaf(rv, wrS[j * 8 + h], acc[e][h]);
        }
      }
    }
#pragma unroll
    for (int h = 0; h < 8; ++h) {
      float4 o;
      o.x = acc[0][h]; o.y = acc[1][h]; o.z = acc[2][h]; o.w = acc[3][h];
      *(float4*)&scoresS[q][h * SST + 4 * tq] = o;  // lane-consecutive
    }
  }
  __syncthreads();

  // ---- phase B: scores = bias + 0.125*QK^T (bias read from LDS) ----
  {
    const int tq = t & 255;
    const int hh = t >> 8;
    const int4 mk4 = *(const int4*)(mask + b * PP + 4 * tq);
#pragma unroll 1
    for (int hi = 0; hi < 4; ++hi) {
      const int h = hh * 4 + hi;
      const float4* ktp =
          (const float4*)(Kt + ((size_t)b * 8 + h) * 64 * 1024) + tq;
      float4 a0 = {0.f, 0.f, 0.f, 0.f}, a1 = {0.f, 0.f, 0.f, 0.f};
#pragma unroll 2
      for (int dq = 0; dq < 16; ++dq) {
        float4 qa = *(const float4*)&qS[0][h * 64 + dq * 4];  // bcast
        float4 qb = *(const float4*)&qS[1][h * 64 + dq * 4];
        float4 k0 = ktp[(size_t)(dq * 4 + 0) * 256];
        float4 k1 = ktp[(size_t)(dq * 4 + 1) * 256];
        float4 k2 = ktp[(size_t)(dq * 4 + 2) * 256];
        float4 k3 = ktp[(size_t)(dq * 4 + 3) * 256];
        a0.x = fmaf(qa.x, k0.x, a0.x); a0.y = fmaf(qa.x, k0.y, a0.y);
        a0.z = fmaf(qa.x, k0.z, a0.z); a0.w = fmaf(qa.x, k0.w, a0.w);
        a0.x = fmaf(qa.y, k1.x, a0.x); a0.y = fmaf(qa.y, k1.y, a0.y);
        a0.z = fmaf(qa.y, k1.z, a0.z); a0.w = fmaf(qa.y, k1.w, a0.w);
        a0.x = fmaf(qa.z, k2.x, a0.x); a0.y = fmaf(qa.z, k2.y, a0.y);
        a0.z = fmaf(qa.z, k2.z, a0.z); a0.w = fmaf(qa.z, k2.w, a0.w);
        a0.x = fmaf(qa.w, k3.x, a0.x); a0.y = fmaf(qa.w, k3.y, a0.y);
        a0.z = fmaf(qa.w, k3.z, a0.z); a0.w = fmaf(qa.w, k3.w, a0.w);
        a1.x = fmaf(qb.x, k0.x, a1.x); a1.y = fmaf(qb.x, k0.y, a1.y);
        a1.z = fmaf(qb.x, k0.z, a1.z); a1.w = fmaf(qb.x, k0.w, a1.w);
        a1.x = fmaf(qb.y, k1.x, a1.x); a1.y = fmaf(qb.y, k1.y, a1.y);
        a1.z = fmaf(qb.y, k1.z, a1.z); a1.w = fmaf(qb.y, k1.w, a1.w);
        a1.x = fmaf(qb.z, k2.x, a1.x); a1.y = fmaf(qb.z, k2.y, a1.y);
        a1.z = fmaf(qb.z, k2.z, a1.z); a1.w = fmaf(qb.z, k2.w, a1.w);
        a1.x = fmaf(qb.w, k3.x, a1.x); a1.y = fmaf(qb.w, k3.y, a1.y);
        a1.z = fmaf(qb.w, k3.z, a1.z); a1.w = fmaf(qb.w, k3.w, a1.w);
      }
      float4 b40 = *(const float4*)&scoresS[0][h * SST + 4 * tq];
      float4 b41 = *(const float4*)&scoresS[1][h * SST + 4 * tq];
      float4 s0, s1;
      s0.x = (mk4.x == 0) ? -1e9f : fmaf(a0.x, 0.125f, b40.x);
      s0.y = (mk4.y == 0) ? -1e9f : fmaf(a0.y, 0.125f, b40.y);
      s0.z = (mk4.z == 0) ? -1e9f : fmaf(a0.z, 0.125f, b40.z);
      s0.w = (mk4.w == 0) ? -1e9f : fmaf(a0.w, 0.125f, b40.w);
      s1.x = (mk4.x == 0) ? -1e9f : fmaf(a1.x, 0.125f, b41.x);
      s1.y = (mk4.y == 0) ? -1e9f : fmaf(a1.y, 0.125f, b41.y);
      s1.z = (mk4.z == 0) ? -1e9f : fmaf(a1.z, 0.125f, b41.z);
      s1.w = (mk4.w == 0) ? -1e9f : fmaf(a1.w, 0.125f, b41.w);
      *(float4*)&scoresS[0][h * SST + 4 * tq] = s0;
      *(float4*)&scoresS[1][h * SST + 4 * tq] = s1;
    }
  }
  __syncthreads();

  // ---- softmax over P: 16 (q,h) rows, 2 per wave ----
  {
    const int wave = t >> 6, lane = t & 63;
    for (int pr = wave * 2; pr < wave * 2 + 2; ++pr) {
      float* sc = &scoresS[pr >> 3][(pr & 7) * SST];
      float m = -3.0e38f;
      for (int i = lane; i < PP; i += 64) m = fmaxf(m, sc[i]);
#pragma unroll
      for (int off = 32; off; off >>= 1) m = fmaxf(m, __shfl_xor(m, off, 64));
      float sum = 0.f;
      for (int i = lane; i < PP; i += 64) {
        float e = __expf(sc[i] - m);
        sc[i] = e;
        sum += e;
      }
#pragma unroll
      for (int off = 32; off; off >>= 1) sum += __shfl_xor(sum, off, 64);
      const float inv = 1.0f / sum;
      for (int i = lane; i < PP; i += 64) sc[i] *= inv;
    }
  }
  __syncthreads();

  // ---- attn_mean: q = t>>8, p-quad = t&255 ----
  {
    const int q = t >> 8, pq = t & 255;
    float4 s = {0.f, 0.f, 0.f, 0.f};
#pragma unroll
    for (int h = 0; h < 8; ++h) {
      float4 v = *(const float4*)&scoresS[q][h * SST + 4 * pq];
      s.x += v.x; s.y += v.y; s.z += v.z; s.w += v.w;
    }
    s.x *= 0.125f; s.y *= 0.125f; s.z *= 0.125f; s.w *= 0.125f;
    const size_t base =
        (size_t)BB * LL * DD + (size_t)(bl0 + q) * PP + 4 * pq;
    if (f32) {
      *(float4*)((float*)d_out + base) = s;
    } else {
      __hip_bfloat16* o1 = (__hip_bfloat16*)d_out;
      o1[base + 0] = __float2bfloat16(s.x);
      o1[base + 1] = __float2bfloat16(s.y);
      o1[base + 2] = __float2bfloat16(s.z);
      o1[base + 3] = __float2bfloat16(s.w);
    }
  }

  // ---- PV: thread owns c-quad (cq) and p-quarter (ph); both queries ----
  float4 pa0, pa1;
  {
    const int cq = t & 127;
    const int ph = t >> 7;  // 0..3, 256 p each
    const int h = cq >> 4;
    const float* sc0 = &scoresS[0][h * SST];
    const float* sc1 = &scoresS[1][h * SST];
    const float4* Vb = (const float4*)(V + (size_t)b * PP * 512) + cq;
    float4 A0 = {0.f, 0.f, 0.f, 0.f}, A1 = {0.f, 0.f, 0.f, 0.f};
    const int p0 = ph * 256;
#pragma unroll 2
    for (int p4 = p0; p4 < p0 + 256; p4 += 4) {
      float4 pr0 = *(const float4*)&sc0[p4];
      float4 pr1 = *(const float4*)&sc1[p4];
      float4 v0 = Vb[(size_t)(p4 + 0) * 128];
      float4 v1 = Vb[(size_t)(p4 + 1) * 128];
      float4 v2 = Vb[(size_t)(p4 + 2) * 128];
      float4 v3 = Vb[(size_t)(p4 + 3) * 128];
      A0.x = fmaf(pr0.x, v0.x, A0.x); A0.y = fmaf(pr0.x, v0.y, A0.y);
      A0.z = fmaf(pr0.x, v0.z, A0.z); A0.w = fmaf(pr0.x, v0.w, A0.w);
      A0.x = fmaf(pr0.y, v1.x, A0.x); A0.y = fmaf(pr0.y, v1.y, A0.y);
      A0.z = fmaf(pr0.y, v1.z, A0.z); A0.w = fmaf(pr0.y, v1.w, A0.w);
      A0.x = fmaf(pr0.z, v2.x, A0.x); A0.y = fmaf(pr0.z, v2.y, A0.y);
      A0.z = fmaf(pr0.z, v2.z, A0.z); A0.w = fmaf(pr0.z, v2.w, A0.w);
      A0.x = fmaf(pr0.w, v3.x, A0.x); A0.y = fmaf(pr0.w, v3.y, A0.y);
      A0.z = fmaf(pr0.w, v3.z, A0.z); A0.w = fmaf(pr0.w, v3.w, A0.w);
      A1.x = fmaf(pr1.x, v0.x, A1.x); A1.y = fmaf(pr1.x, v0.y, A1.y);
      A1.z = fmaf(pr1.x, v0.z, A1.z); A1.w = fmaf(pr1.x, v0.w, A1.w);
      A1.x = fmaf(pr1.y, v1.x, A1.x); A1.y = fmaf(pr1.y, v1.y, A1.y);
      A1.z = fmaf(pr1.y, v1.z, A1.z); A1.w = fmaf(pr1.y, v1.w, A1.w);
      A1.x = fmaf(pr1.z, v2.x, A1.x); A1.y = fmaf(pr1.z, v2.y, A1.y);
      A1.z = fmaf(pr1.z, v2.z, A1.z); A1.w = fmaf(pr1.z, v2.w, A1.w);
      A1.x = fmaf(pr1.w, v3.x, A1.x); A1.y = fmaf(pr1.w, v3.y, A1.y);
      A1.z = fmaf(pr1.w, v3.z, A1.z); A1.w = fmaf(pr1.w, v3.w, A1.w);
    }
    pa0 = A0;
    pa1 = A1;
  }
  __syncthreads();  // all score reads complete; safe to reuse LDS
  {
    const int cq = t & 127, ph = t >> 7;
    float* parts = &scoresS[0][0];  // [2 q][4 ph][128 cq][4] = 16 KB alias
    *(float4*)&parts[((0 * 4 + ph) * 128 + cq) * 4] = pa0;
    *(float4*)&parts[((1 * 4 + ph) * 128 + cq) * 4] = pa1;
  }
  __syncthreads();
  if (t < 256) {
    const int q = t >> 7, c = t & 127;
    const float* parts = &scoresS[0][0];
    float4 a = *(const float4*)&parts[((q * 4 + 0) * 128 + c) * 4];
#pragma unroll
    for (int ph = 1; ph < 4; ++ph) {
      float4 x = *(const float4*)&parts[((q * 4 + ph) * 128 + c) * 4];
      a.x += x.x; a.y += x.y; a.z += x.z; a.w += x.w;
    }
    *(float4*)&AO[(size_t)(bl0 + q) * 512 + 4 * c] = a;
  }
}

// ---------------------------------------------------------------------------
// Output projection + residual: Xout = AO@Wo + bo + query   (fp32 ws)
// ---------------------------------------------------------------------------
__global__ __launch_bounds__(256) void proj_out(
    const float* __restrict__ X, const void* __restrict__ W,
    const void* __restrict__ bias, const void* __restrict__ resid,
    float* __restrict__ Y, const int* __restrict__ flag) {
  __shared__ float As[16][64];
  __shared__ float Bs[16][64];
  const bool f32 = (*flag != 0);
  const int bm = blockIdx.x * 64, bn = blockIdx.y * 64;
  const int tid = threadIdx.x;
  const int tx = tid & 15, ty = tid >> 4;
  float acc[4][4] = {};
  for (int k0 = 0; k0 < 512; k0 += 16) {
    {
      int r = tid >> 2, kf = (tid & 3) * 4;
      float4 x4 = *(const float4*)(X + (size_t)(bm + r) * 512 + k0 + kf);
      As[kf + 0][r] = x4.x; As[kf + 1][r] = x4.y;
      As[kf + 2][r] = x4.z; As[kf + 3][r] = x4.w;
    }
    if (f32) {
      int kk = tid >> 4, cf = (tid & 15) * 4;
      *(float4*)&Bs[kk][cf] =
          *(const float4*)((const float*)W + (size_t)(k0 + kk) * 512 + bn + cf);
    } else {
      const unsigned short* Wb = (const unsigned short*)W;
      for (int f = tid; f < 16 * 64; f += 256) {
        int kk = f >> 6, c = f & 63;
        Bs[kk][c] = bf2f(Wb[(size_t)(k0 + kk) * 512 + bn + c]);
      }
    }
    __syncthreads();
#pragma unroll
    for (int k = 0; k < 16; ++k) {
      float4 a4 = *(const float4*)&As[k][ty * 4];
      float4 b4 = *(const float4*)&Bs[k][tx * 4];
      acc[0][0] = fmaf(a4.x, b4.x, acc[0][0]); acc[0][1] = fmaf(a4.x, b4.y, acc[0][1]);
      acc[0][2] = fmaf(a4.x, b4.z, acc[0][2]); acc[0][3] = fmaf(a4.x, b4.w, acc[0][3]);
      acc[1][0] = fmaf(a4.y, b4.x, acc[1][0]); acc[1][1] = fmaf(a4.y, b4.y, acc[1][1]);
      acc[1][2] = fmaf(a4.y, b4.z, acc[1][2]); acc[1][3] = fmaf(a4.y, b4.w, acc[1][3]);
      acc[2][0] = fmaf(a4.z, b4.x, acc[2][0]); acc[2][1] = fmaf(a4.z, b4.y, acc[2][1]);
      acc[2][2] = fmaf(a4.z, b4.z, acc[2][2]); acc[2][3] = fmaf(a4.z, b4.w, acc[2][3]);
      acc[3][0] = fmaf(a4.w, b4.x, acc[3][0]); acc[3][1] = fmaf(a4.w, b4.y, acc[3][1]);
      acc[3][2] = fmaf(a4.w, b4.z, acc[3][2]); acc[3][3] = fmaf(a4.w, b4.w, acc[3][3]);
    }
    __syncthreads();
  }
#pragma unroll
  for (int i = 0; i < 4; ++i) {
    int r = bm + ty * 4 + i;
    float4 o;
#pragma unroll
    for (int j = 0; j < 4; ++j) {
      int c = bn + tx * 4 + j;
      float v = acc[i][j] + ldf(bias, c, f32) +
                ldf(resid, (size_t)r * 512 + c, f32);
      ((float*)&o)[j] = v;
    }
    *(float4*)(Y + (size_t)r * 512 + bn + tx * 4) = o;
  }
}

// ---------------------------------------------------------------------------
// LayerNorm rows of Xw -> out0
// ---------------------------------------------------------------------------
__global__ __launch_bounds__(256) void ln_kernel(
    const float* __restrict__ Xw, const void* __restrict__ gamma,
    const void* __restrict__ beta, void* __restrict__ d_out,
    const int* __restrict__ flag) {
  const int bl = blockIdx.x;
  const int tid = threadIdx.x;
  const bool f32 = (*flag != 0);
  __shared__ float red[16];
  float v0 = Xw[(size_t)bl * 512 + tid];
  float v1 = Xw[(size_t)bl * 512 + tid + 256];
  float s = v0 + v1, s2 = v0 * v0 + v1 * v1;
#pragma unroll
  for (int off = 32; off; off >>= 1) {
    s += __shfl_xor(s, off, 64);
    s2 += __shfl_xor(s2, off, 64);
  }
  const int wave = tid >> 6, lane = tid & 63;
  if (lane == 0) { red[wave] = s; red[8 + wave] = s2; }
  __syncthreads();
  if (tid == 0) {
    float ts = 0.f, ts2 = 0.f;
    for (int w = 0; w < 4; ++w) { ts += red[w]; ts2 += red[8 + w]; }
    red[0] = ts; red[1] = ts2;
  }
  __syncthreads();
  const float mu = red[0] * (1.0f / 512.0f);
  const float var = red[1] * (1.0f / 512.0f) - mu * mu;
  const float rstd = rsqrtf(var + 1e-5f);
  float o0 = (v0 - mu) * rstd * ldf(gamma, tid, f32) + ldf(beta, tid, f32);
  float o1 = (v1 - mu) * rstd * ldf(gamma, tid + 256, f32) +
             ldf(beta, tid + 256, f32);
  if (f32) {
    float* o = (float*)d_out;
    o[(size_t)bl * 512 + tid] = o0;
    o[(size_t)bl * 512 + tid + 256] = o1;
  } else {
    __hip_bfloat16* o = (__hip_bfloat16*)d_out;
    o[(size_t)bl * 512 + tid] = __float2bfloat16(o0);
    o[(size_t)bl * 512 + tid + 256] = __float2bfloat16(o1);
  }
}

// ---------------------------------------------------------------------------
extern "C" void kernel_launch(void* const* d_in, const int* in_sizes, int n_in,
                              void* d_out, int out_size, void* d_ws,
                              size_t ws_size, hipStream_t stream) {
  const void* query = d_in[0];
  const void* key = d_in[1];
  const void* value = d_in[2];
  const void* rbf = d_in[3];
  const int* key_mask = (const int*)d_in[4];
  const void* Wq = d_in[5];
  const void* bq = d_in[6];
  const void* Wk = d_in[7];
  const void* bk = d_in[8];
  const void* Wv = d_in[9];
  const void* bv = d_in[10];
  const void* Wr = d_in[11];
  const void* br = d_in[12];
  const void* Wo = d_in[13];
  const void* bo = d_in[14];
  const void* gamma = d_in[15];
  const void* beta = d_in[16];

  // ws: [flag 16B] Q | Kt | V | AO | X
  int* flag = (int*)d_ws;
  float* base = (float*)d_ws + 4;
  float* Qw = base;
  float* Ktw = Qw + (size_t)BB * LL * DD;   // +524288
  float* Vw = Ktw + (size_t)BB * PP * DD;   // +2097152
  float* AO = Vw + (size_t)BB * PP * DD;    // +2097152
  float* Xw = AO + (size_t)BB * LL * DD;    // +524288

  detect_dtype<<<1, 256, 0, stream>>>((const float*)query, flag);
  qkv_gemm<<<dim3(288), 256, 0, stream>>>(query, key, value, Wq, bq, Wk, bk,
                                          Wv, bv, Qw, Ktw, Vw, flag);
  attn_v9<<<dim3(BB * LL / 2), 512, 0, stream>>>(Qw, Ktw, Vw, rbf, Wr, br,
                                                 key_mask, AO, d_out, flag);
  proj_out<<<dim3(16, 8), 256, 0, stream>>>(AO, Wo, bo, query, Xw, flag);
  ln_kernel<<<dim3(BB * LL), 256, 0, stream>>>(Xw, gamma, beta, d_out, flag);
}

// Round 7
// 609.540 us; speedup vs baseline: 1.5848x; 1.2196x over previous
//
#include <hip/hip_runtime.h>
#include <hip/hip_bf16.h>

#define BB 4
#define LL 256
#define PP 1024
#define DD 512
#define HH 8
#define HD 64
#define NRBF 50

// ---------------------------------------------------------------------------
// dtype helpers (inputs are fp32 per reference; bf16 fallback kept for safety)
// ---------------------------------------------------------------------------
__device__ __forceinline__ float bf2f(unsigned short u) {
  return __uint_as_float((unsigned)u << 16);
}

__device__ __forceinline__ float ldf(const void* p, size_t i, bool f32) {
  if (f32) return ((const float*)p)[i];
  return bf2f(((const unsigned short*)p)[i]);
}

__device__ __forceinline__ float4 ld4e(const void* p, size_t i, bool f32) {
  if (f32) return *(const float4*)((const float*)p + i);
  ushort4 u = *(const ushort4*)((const unsigned short*)p + i);
  float4 r;
  r.x = bf2f(u.x); r.y = bf2f(u.y); r.z = bf2f(u.z); r.w = bf2f(u.w);
  return r;
}

__global__ __launch_bounds__(256) void detect_dtype(const float* q, int* flag) {
  __shared__ int cnt;
  if (threadIdx.x == 0) cnt = 0;
  __syncthreads();
  int c = 0;
  for (int i = threadIdx.x; i < 1024; i += 256) {
    unsigned u = __float_as_uint(q[i]);
    unsigned e = (u >> 23) & 0xffu;
    if (e >= 104u && e <= 140u) c++;
  }
  atomicAdd(&cnt, c);
  __syncthreads();
  if (threadIdx.x == 0) *flag = (cnt > 512) ? 1 : 0;
}

// ---------------------------------------------------------------------------
// 128x128-tile fp32 GEMM core, 8x8 per thread (quad-split), double-buffered.
// mode 0: Y[m][512] = X@W + bias        (normal row-major)
// mode 1: Kt[b][h][d][p] transposed head-major output (m = b*1024+p, n=h*64+d)
// ---------------------------------------------------------------------------
__device__ void gemm128(const void* __restrict__ X, const void* __restrict__ W,
                        const void* __restrict__ bias, float* __restrict__ Y,
                        const int bm, const int bn, const int mode,
                        const bool f32, float* lds) {
  const int tid = threadIdx.x;
  const int tx = tid & 15, ty = tid >> 4;
  const int lr = tid >> 1, lc = (tid & 1) * 8;   // A staging: row, col0
  const int wk = tid >> 5, wc = (tid & 31) * 4;  // B staging: k-row, col
  float acc[8][8] = {};
  float4 ra0, ra1, rb0, rb1;

  // prologue: tile 0 -> regs -> buf 0
  ra0 = ld4e(X, (size_t)(bm + lr) * 512 + lc, f32);
  ra1 = ld4e(X, (size_t)(bm + lr) * 512 + lc + 4, f32);
  rb0 = ld4e(W, (size_t)wk * 512 + bn + wc, f32);
  rb1 = ld4e(W, (size_t)(wk + 8) * 512 + bn + wc, f32);
  {
    float* Ab = lds;
    float* Bb = lds + 4096;
    Ab[(lc + 0) * 128 + lr] = ra0.x; Ab[(lc + 1) * 128 + lr] = ra0.y;
    Ab[(lc + 2) * 128 + lr] = ra0.z; Ab[(lc + 3) * 128 + lr] = ra0.w;
    Ab[(lc + 4) * 128 + lr] = ra1.x; Ab[(lc + 5) * 128 + lr] = ra1.y;
    Ab[(lc + 6) * 128 + lr] = ra1.z; Ab[(lc + 7) * 128 + lr] = ra1.w;
    *(float4*)&Bb[wk * 128 + wc] = rb0;
    *(float4*)&Bb[(wk + 8) * 128 + wc] = rb1;
  }
  __syncthreads();

  int buf = 0;
  for (int tt = 0; tt < 32; ++tt) {
    if (tt < 31) {  // issue next tile's global loads (overlap with compute)
      const int k0 = (tt + 1) * 16;
      ra0 = ld4e(X, (size_t)(bm + lr) * 512 + k0 + lc, f32);
      ra1 = ld4e(X, (size_t)(bm + lr) * 512 + k0 + lc + 4, f32);
      rb0 = ld4e(W, (size_t)(k0 + wk) * 512 + bn + wc, f32);
      rb1 = ld4e(W, (size_t)(k0 + wk + 8) * 512 + bn + wc, f32);
    }
    {
      const float* Ab = lds + buf * 2048;
      const float* Bb = lds + 4096 + buf * 2048;
#pragma unroll
      for (int k = 0; k < 16; ++k) {
        float4 aL = *(const float4*)&Ab[k * 128 + ty * 4];
        float4 aH = *(const float4*)&Ab[k * 128 + 64 + ty * 4];
        float4 bL = *(const float4*)&Bb[k * 128 + tx * 4];
        float4 bH = *(const float4*)&Bb[k * 128 + 64 + tx * 4];
        const float a8[8] = {aL.x, aL.y, aL.z, aL.w, aH.x, aH.y, aH.z, aH.w};
        const float b8[8] = {bL.x, bL.y, bL.z, bL.w, bH.x, bH.y, bH.z, bH.w};
#pragma unroll
        for (int i = 0; i < 8; ++i)
#pragma unroll
          for (int j = 0; j < 8; ++j)
            acc[i][j] = fmaf(a8[i], b8[j], acc[i][j]);
      }
    }
    if (tt < 31) {  // stage next tile into the other buffer
      float* Ab = lds + (buf ^ 1) * 2048;
      float* Bb = lds + 4096 + (buf ^ 1) * 2048;
      Ab[(lc + 0) * 128 + lr] = ra0.x; Ab[(lc + 1) * 128 + lr] = ra0.y;
      Ab[(lc + 2) * 128 + lr] = ra0.z; Ab[(lc + 3) * 128 + lr] = ra0.w;
      Ab[(lc + 4) * 128 + lr] = ra1.x; Ab[(lc + 5) * 128 + lr] = ra1.y;
      Ab[(lc + 6) * 128 + lr] = ra1.z; Ab[(lc + 7) * 128 + lr] = ra1.w;
      *(float4*)&Bb[wk * 128 + wc] = rb0;
      *(float4*)&Bb[(wk + 8) * 128 + wc] = rb1;
    }
    __syncthreads();
    buf ^= 1;
  }

  if (mode == 0) {
#pragma unroll
    for (int rh = 0; rh < 2; ++rh)
#pragma unroll
      for (int i = 0; i < 4; ++i) {
        const int r = bm + rh * 64 + ty * 4 + i;
#pragma unroll
        for (int ch = 0; ch < 2; ++ch) {
          const int c = bn + ch * 64 + tx * 4;
          float4 o;
          o.x = acc[rh * 4 + i][ch * 4 + 0] + ldf(bias, c + 0, f32);
          o.y = acc[rh * 4 + i][ch * 4 + 1] + ldf(bias, c + 1, f32);
          o.z = acc[rh * 4 + i][ch * 4 + 2] + ldf(bias, c + 2, f32);
          o.w = acc[rh * 4 + i][ch * 4 + 3] + ldf(bias, c + 3, f32);
          *(float4*)&Y[(size_t)r * 512 + c] = o;
        }
      }
  } else {
    const int bq = bm >> 10;
    const int pb = bm & 1023;
#pragma unroll
    for (int ch = 0; ch < 2; ++ch)
#pragma unroll
      for (int j = 0; j < 4; ++j) {
        const int c = bn + ch * 64 + tx * 4 + j;  // h = c>>6, d = c&63
        const float bb = ldf(bias, c, f32);
#pragma unroll
        for (int rh = 0; rh < 2; ++rh) {
          float4 pv;
          pv.x = acc[rh * 4 + 0][ch * 4 + j] + bb;
          pv.y = acc[rh * 4 + 1][ch * 4 + j] + bb;
          pv.z = acc[rh * 4 + 2][ch * 4 + j] + bb;
          pv.w = acc[rh * 4 + 3][ch * 4 + j] + bb;
          const int p0 = pb + rh * 64 + ty * 4;
          *(float4*)&Y[(((size_t)bq * 8 + (c >> 6)) * 64 + (c & 63)) * 1024 +
                       p0] = pv;
        }
      }
  }
}

// ---------------------------------------------------------------------------
// Q/K/V projections only (rbf lives inside attention).
// ---------------------------------------------------------------------------
__global__ __launch_bounds__(256) void qkv_gemm(
    const void* __restrict__ query, const void* __restrict__ key,
    const void* __restrict__ value, const void* __restrict__ Wq,
    const void* __restrict__ bq_, const void* __restrict__ Wk,
    const void* __restrict__ bk_, const void* __restrict__ Wv,
    const void* __restrict__ bv_, float* __restrict__ Qw,
    float* __restrict__ Ktw, float* __restrict__ Vw,
    const int* __restrict__ flag) {
  __shared__ float lds[8192];  // 32 KB double buffers
  const bool f32 = (*flag != 0);
  const int blk = blockIdx.x;

  const void *X, *W, *bias;
  float* Y;
  int mode, mi, ni;
  if (blk < 32) {
    X = query; W = Wq; bias = bq_; Y = Qw; mode = 0;
    mi = blk >> 2; ni = blk & 3;
  } else if (blk < 160) {
    const int q2 = blk - 32;
    X = key; W = Wk; bias = bk_; Y = Ktw; mode = 1;
    mi = q2 >> 2; ni = q2 & 3;
  } else {
    const int q2 = blk - 160;
    X = value; W = Wv; bias = bv_; Y = Vw; mode = 0;
    mi = q2 >> 2; ni = q2 & 3;
  }
  gemm128(X, W, bias, Y, mi * 128, ni * 128, mode, f32, lds);
}

// ---------------------------------------------------------------------------
// Attention v10: 4 queries/block, 256 blocks (1/CU), 512 threads.
// vs v9: (a) Kt/V are each read once per 4 queries -> L2-fill traffic for
// K/V halves (was the FETCH excess: 609 MB vs 245 unique); (b) phase A rbf
// loop at unroll 5 -> 5 outstanding loads/thread (~40 KB/CU in flight),
// lifting the rbf stream off the latency floor (was 2 loads, ~16 KB).
// LDS: scores 4x8x1028 (131.6 KB) + q 8 KB + wr 1.6 KB = ~141 KB < 160 KB.
// ---------------------------------------------------------------------------
#define SST 1028  // padded score stride

__global__ __launch_bounds__(512) void attn_v10(
    const float* __restrict__ Q,     // [B*L, 512]
    const float* __restrict__ Kt,    // [B][8][64][1024]
    const float* __restrict__ V,     // [B*P, 512]
    const void* __restrict__ rbf,    // [B*L*P, 50]
    const void* __restrict__ Wr,     // [50, 8]
    const void* __restrict__ br_,    // [8]
    const int* __restrict__ mask,    // [B,P]
    float* __restrict__ AO,          // [B*L, 512]
    void* __restrict__ d_out, const int* __restrict__ flag) {
  const int xcd = blockIdx.x & 7;
  const int idx = blockIdx.x >> 3;          // 0..31
  const int b = xcd >> 1;
  const int lq = ((xcd & 1) << 5) | idx;    // 0..63
  const int bl0 = b * LL + lq * 4;          // first of 4 queries
  const int t = threadIdx.x;
  const bool f32 = (*flag != 0);

  __shared__ float qS[4][512];              // 8 KB
  __shared__ float wrS[NRBF * 8];           // 1.6 KB
  __shared__ float brS[8];
  __shared__ float scoresS[4][8 * SST];     // 131.6 KB

  for (int i = t; i < 2048; i += 512)
    qS[i >> 9][i & 511] = Q[(size_t)bl0 * 512 + i];
  for (int i = t; i < NRBF * 8; i += 512) wrS[i] = ldf(Wr, i, f32);
  if (t < 8) brS[t] = ldf(br_, t, f32);
  __syncthreads();

  // ---- phase A: rbf bias -> scoresS. thread (qh = t>>8, tq = t&255)
  //      handles queries {2qh, 2qh+1}, rows p = 4tq..4tq+3 each. ----
  {
    const int qh = t >> 8;
    const int tq = t & 255;
#pragma unroll
    for (int qi = 0; qi < 2; ++qi) {
      const int q = qh * 2 + qi;
      float acc[4][8];
#pragma unroll
      for (int e = 0; e < 4; ++e)
#pragma unroll
        for (int h = 0; h < 8; ++h) acc[e][h] = brS[h];
      const size_t rbase = ((size_t)(bl0 + q) * 1024 + 4 * tq) * NRBF;
      if (f32) {
        const float* rowb = (const float*)rbf + rbase;
#pragma unroll
        for (int e = 0; e < 4; ++e) {
          const float2* rp = (const float2*)(rowb + e * NRBF);  // 8-B aligned
#pragma unroll 5
          for (int j = 0; j < 25; ++j) {
            const float2 r2 = rp[j];
            const float4 wa = *(const float4*)&wrS[(2 * j) * 8];
            const float4 wb = *(const float4*)&wrS[(2 * j) * 8 + 4];
            const float4 wc = *(const float4*)&wrS[(2 * j + 1) * 8];
            const float4 wd = *(const float4*)&wrS[(2 * j + 1) * 8 + 4];
            acc[e][0] = fmaf(r2.x, wa.x, acc[e][0]);
            acc[e][1] = fmaf(r2.x, wa.y, acc[e][1]);
            acc[e][2] = fmaf(r2.x, wa.z, acc[e][2]);
            acc[e][3] = fmaf(r2.x, wa.w, acc[e][3]);
            acc[e][4] = fmaf(r2.x, wb.x, acc[e][4]);
            acc[e][5] = fmaf(r2.x, wb.y, acc[e][5]);
            acc[e][6] = fmaf(r2.x, wb.z, acc[e][6]);
            acc[e][7] = fmaf(r2.x, wb.w, acc[e][7]);
            acc[e][0] = fmaf(r2.y, wc.x, acc[e][0]);
            acc[e][1] = fmaf(r2.y, wc.y, acc[e][1]);
            acc[e][2] = fmaf(r2.y, wc.z, acc[e][2]);
            acc[e][3] = fmaf(r2.y, wc.w, acc[e][3]);
            acc[e][4] = fmaf(r2.y, wd.x, acc[e][4]);
            acc[e][5] = fmaf(r2.y, wd.y, acc[e][5]);
            acc[e][6] = fmaf(r2.y, wd.z, acc[e][6]);
            acc[e][7] = fmaf(r2.y, wd.w, acc[e][7]);
          }
        }
      } else {
        const unsigned short* rb = (const unsigned short*)rbf + rbase;
#pragma unroll
        for (int e = 0; e < 4; ++e) {
#pragma unroll 1
          for (int j = 0; j < 50; ++j) {
            const float rv = bf2f(rb[e * 50 + j]);
#pragma unroll
            for (int h = 0; h < 8; ++h)
              acc[e][h] = fmaf(rv, wrS[j * 8 + h], acc[e][h]);
          }
        }
      }
#pragma unroll
      for (int h = 0; h < 8; ++h) {
        float4 o;
        o.x = acc[0][h]; o.y = acc[1][h]; o.z = acc[2][h]; o.w = acc[3][h];
        *(float4*)&scoresS[q][h * SST + 4 * tq] = o;  // lane-consecutive
      }
    }
  }
  __syncthreads();

  // ---- phase B: scores = bias + 0.125*QK^T; one Kt read serves 4 q ----
  {
    const int tq = t & 255;
    const int hh = t >> 8;
    const int4 mk4 = *(const int4*)(mask + b * PP + 4 * tq);
#pragma unroll 1
    for (int hi = 0; hi < 4; ++hi) {
      const int h = hh * 4 + hi;
      const float4* ktp =
          (const float4*)(Kt + ((size_t)b * 8 + h) * 64 * 1024) + tq;
      float4 a0 = {0.f, 0.f, 0.f, 0.f}, a1 = {0.f, 0.f, 0.f, 0.f};
      float4 a2 = {0.f, 0.f, 0.f, 0.f}, a3 = {0.f, 0.f, 0.f, 0.f};
#pragma unroll 2
      for (int dq = 0; dq < 16; ++dq) {
        float4 q0 = *(const float4*)&qS[0][h * 64 + dq * 4];  // bcast
        float4 q1 = *(const float4*)&qS[1][h * 64 + dq * 4];
        float4 q2 = *(const float4*)&qS[2][h * 64 + dq * 4];
        float4 q3 = *(const float4*)&qS[3][h * 64 + dq * 4];
        float4 k0 = ktp[(size_t)(dq * 4 + 0) * 256];
        float4 k1 = ktp[(size_t)(dq * 4 + 1) * 256];
        float4 k2 = ktp[(size_t)(dq * 4 + 2) * 256];
        float4 k3 = ktp[(size_t)(dq * 4 + 3) * 256];
        a0.x = fmaf(q0.x, k0.x, a0.x); a0.y = fmaf(q0.x, k0.y, a0.y);
        a0.z = fmaf(q0.x, k0.z, a0.z); a0.w = fmaf(q0.x, k0.w, a0.w);
        a0.x = fmaf(q0.y, k1.x, a0.x); a0.y = fmaf(q0.y, k1.y, a0.y);
        a0.z = fmaf(q0.y, k1.z, a0.z); a0.w = fmaf(q0.y, k1.w, a0.w);
        a0.x = fmaf(q0.z, k2.x, a0.x); a0.y = fmaf(q0.z, k2.y, a0.y);
        a0.z = fmaf(q0.z, k2.z, a0.z); a0.w = fmaf(q0.z, k2.w, a0.w);
        a0.x = fmaf(q0.w, k3.x, a0.x); a0.y = fmaf(q0.w, k3.y, a0.y);
        a0.z = fmaf(q0.w, k3.z, a0.z); a0.w = fmaf(q0.w, k3.w, a0.w);
        a1.x = fmaf(q1.x, k0.x, a1.x); a1.y = fmaf(q1.x, k0.y, a1.y);
        a1.z = fmaf(q1.x, k0.z, a1.z); a1.w = fmaf(q1.x, k0.w, a1.w);
        a1.x = fmaf(q1.y, k1.x, a1.x); a1.y = fmaf(q1.y, k1.y, a1.y);
        a1.z = fmaf(q1.y, k1.z, a1.z); a1.w = fmaf(q1.y, k1.w, a1.w);
        a1.x = fmaf(q1.z, k2.x, a1.x); a1.y = fmaf(q1.z, k2.y, a1.y);
        a1.z = fmaf(q1.z, k2.z, a1.z); a1.w = fmaf(q1.z, k2.w, a1.w);
        a1.x = fmaf(q1.w, k3.x, a1.x); a1.y = fmaf(q1.w, k3.y, a1.y);
        a1.z = fmaf(q1.w, k3.z, a1.z); a1.w = fmaf(q1.w, k3.w, a1.w);
        a2.x = fmaf(q2.x, k0.x, a2.x); a2.y = fmaf(q2.x, k0.y, a2.y);
        a2.z = fmaf(q2.x, k0.z, a2.z); a2.w = fmaf(q2.x, k0.w, a2.w);
        a2.x = fmaf(q2.y, k1.x, a2.x); a2.y = fmaf(q2.y, k1.y, a2.y);
        a2.z = fmaf(q2.y, k1.z, a2.z); a2.w = fmaf(q2.y, k1.w, a2.w);
        a2.x = fmaf(q2.z, k2.x, a2.x); a2.y = fmaf(q2.z, k2.y, a2.y);
        a2.z = fmaf(q2.z, k2.z, a2.z); a2.w = fmaf(q2.z, k2.w, a2.w);
        a2.x = fmaf(q2.w, k3.x, a2.x); a2.y = fmaf(q2.w, k3.y, a2.y);
        a2.z = fmaf(q2.w, k3.z, a2.z); a2.w = fmaf(q2.w, k3.w, a2.w);
        a3.x = fmaf(q3.x, k0.x, a3.x); a3.y = fmaf(q3.x, k0.y, a3.y);
        a3.z = fmaf(q3.x, k0.z, a3.z); a3.w = fmaf(q3.x, k0.w, a3.w);
        a3.x = fmaf(q3.y, k1.x, a3.x); a3.y = fmaf(q3.y, k1.y, a3.y);
        a3.z = fmaf(q3.y, k1.z, a3.z); a3.w = fmaf(q3.y, k1.w, a3.w);
        a3.x = fmaf(q3.z, k2.x, a3.x); a3.y = fmaf(q3.z, k2.y, a3.y);
        a3.z = fmaf(q3.z, k2.z, a3.z); a3.w = fmaf(q3.z, k2.w, a3.w);
        a3.x = fmaf(q3.w, k3.x, a3.x); a3.y = fmaf(q3.w, k3.y, a3.y);
        a3.z = fmaf(q3.w, k3.z, a3.z); a3.w = fmaf(q3.w, k3.w, a3.w);
      }
      float4 av[4] = {a0, a1, a2, a3};
#pragma unroll
      for (int qi = 0; qi < 4; ++qi) {
        float4 bq4 = *(const float4*)&scoresS[qi][h * SST + 4 * tq];
        float4 s;
        s.x = (mk4.x == 0) ? -1e9f : fmaf(av[qi].x, 0.125f, bq4.x);
        s.y = (mk4.y == 0) ? -1e9f : fmaf(av[qi].y, 0.125f, bq4.y);
        s.z = (mk4.z == 0) ? -1e9f : fmaf(av[qi].z, 0.125f, bq4.z);
        s.w = (mk4.w == 0) ? -1e9f : fmaf(av[qi].w, 0.125f, bq4.w);
        *(float4*)&scoresS[qi][h * SST + 4 * tq] = s;
      }
    }
  }
  __syncthreads();

  // ---- softmax over P: 32 (q,h) rows, 4 per wave ----
  {
    const int wave = t >> 6, lane = t & 63;
    for (int pr = wave * 4; pr < wave * 4 + 4; ++pr) {
      float* sc = &scoresS[pr >> 3][(pr & 7) * SST];
      float m = -3.0e38f;
      for (int i = lane; i < PP; i += 64) m = fmaxf(m, sc[i]);
#pragma unroll
      for (int off = 32; off; off >>= 1) m = fmaxf(m, __shfl_xor(m, off, 64));
      float sum = 0.f;
      for (int i = lane; i < PP; i += 64) {
        float e = __expf(sc[i] - m);
        sc[i] = e;
        sum += e;
      }
#pragma unroll
      for (int off = 32; off; off >>= 1) sum += __shfl_xor(sum, off, 64);
      const float inv = 1.0f / sum;
      for (int i = lane; i < PP; i += 64) sc[i] *= inv;
    }
  }
  __syncthreads();

  // ---- attn_mean: 4 q x 256 p-quads = 1024 units, 2 per thread ----
  for (int w = t; w < 1024; w += 512) {
    const int q = w >> 8, pq = w & 255;
    float4 s = {0.f, 0.f, 0.f, 0.f};
#pragma unroll
    for (int h = 0; h < 8; ++h) {
      float4 v = *(const float4*)&scoresS[q][h * SST + 4 * pq];
      s.x += v.x; s.y += v.y; s.z += v.z; s.w += v.w;
    }
    s.x *= 0.125f; s.y *= 0.125f; s.z *= 0.125f; s.w *= 0.125f;
    const size_t base =
        (size_t)BB * LL * DD + (size_t)(bl0 + q) * PP + 4 * pq;
    if (f32) {
      *(float4*)((float*)d_out + base) = s;
    } else {
      __hip_bfloat16* o1 = (__hip_bfloat16*)d_out;
      o1[base + 0] = __float2bfloat16(s.x);
      o1[base + 1] = __float2bfloat16(s.y);
      o1[base + 2] = __float2bfloat16(s.z);
      o1[base + 3] = __float2bfloat16(s.w);
    }
  }

  // ---- PV: thread owns c-quad (cq) and p-quarter (ph); 4 queries ----
  float4 pa[4];
  {
    const int cq = t & 127;
    const int ph = t >> 7;  // 0..3, 256 p each
    const int h = cq >> 4;
    const float* sc0 = &scoresS[0][h * SST];
    const float* sc1 = &scoresS[1][h * SST];
    const float* sc2 = &scoresS[2][h * SST];
    const float* sc3 = &scoresS[3][h * SST];
    const float4* Vb = (const float4*)(V + (size_t)b * PP * 512) + cq;
    float4 A0 = {0.f, 0.f, 0.f, 0.f}, A1 = {0.f, 0.f, 0.f, 0.f};
    float4 A2 = {0.f, 0.f, 0.f, 0.f}, A3 = {0.f, 0.f, 0.f, 0.f};
    const int p0 = ph * 256;
#pragma unroll 2
    for (int p4 = p0; p4 < p0 + 256; p4 += 4) {
      float4 pr0 = *(const float4*)&sc0[p4];
      float4 pr1 = *(const float4*)&sc1[p4];
      float4 pr2 = *(const float4*)&sc2[p4];
      float4 pr3 = *(const float4*)&sc3[p4];
      float4 v0 = Vb[(size_t)(p4 + 0) * 128];
      float4 v1 = Vb[(size_t)(p4 + 1) * 128];
      float4 v2 = Vb[(size_t)(p4 + 2) * 128];
      float4 v3 = Vb[(size_t)(p4 + 3) * 128];
      A0.x = fmaf(pr0.x, v0.x, A0.x); A0.y = fmaf(pr0.x, v0.y, A0.y);
      A0.z = fmaf(pr0.x, v0.z, A0.z); A0.w = fmaf(pr0.x, v0.w, A0.w);
      A0.x = fmaf(pr0.y, v1.x, A0.x); A0.y = fmaf(pr0.y, v1.y, A0.y);
      A0.z = fmaf(pr0.y, v1.z, A0.z); A0.w = fmaf(pr0.y, v1.w, A0.w);
      A0.x = fmaf(pr0.z, v2.x, A0.x); A0.y = fmaf(pr0.z, v2.y, A0.y);
      A0.z = fmaf(pr0.z, v2.z, A0.z); A0.w = fmaf(pr0.z, v2.w, A0.w);
      A0.x = fmaf(pr0.w, v3.x, A0.x); A0.y = fmaf(pr0.w, v3.y, A0.y);
      A0.z = fmaf(pr0.w, v3.z, A0.z); A0.w = fmaf(pr0.w, v3.w, A0.w);
      A1.x = fmaf(pr1.x, v0.x, A1.x); A1.y = fmaf(pr1.x, v0.y, A1.y);
      A1.z = fmaf(pr1.x, v0.z, A1.z); A1.w = fmaf(pr1.x, v0.w, A1.w);
      A1.x = fmaf(pr1.y, v1.x, A1.x); A1.y = fmaf(pr1.y, v1.y, A1.y);
      A1.z = fmaf(pr1.y, v1.z, A1.z); A1.w = fmaf(pr1.y, v1.w, A1.w);
      A1.x = fmaf(pr1.z, v2.x, A1.x); A1.y = fmaf(pr1.z, v2.y, A1.y);
      A1.z = fmaf(pr1.z, v2.z, A1.z); A1.w = fmaf(pr1.z, v2.w, A1.w);
      A1.x = fmaf(pr1.w, v3.x, A1.x); A1.y = fmaf(pr1.w, v3.y, A1.y);
      A1.z = fmaf(pr1.w, v3.z, A1.z); A1.w = fmaf(pr1.w, v3.w, A1.w);
      A2.x = fmaf(pr2.x, v0.x, A2.x); A2.y = fmaf(pr2.x, v0.y, A2.y);
      A2.z = fmaf(pr2.x, v0.z, A2.z); A2.w = fmaf(pr2.x, v0.w, A2.w);
      A2.x = fmaf(pr2.y, v1.x, A2.x); A2.y = fmaf(pr2.y, v1.y, A2.y);
      A2.z = fmaf(pr2.y, v1.z, A2.z); A2.w = fmaf(pr2.y, v1.w, A2.w);
      A2.x = fmaf(pr2.z, v2.x, A2.x); A2.y = fmaf(pr2.z, v2.y, A2.y);
      A2.z = fmaf(pr2.z, v2.z, A2.z); A2.w = fmaf(pr2.z, v2.w, A2.w);
      A2.x = fmaf(pr2.w, v3.x, A2.x); A2.y = fmaf(pr2.w, v3.y, A2.y);
      A2.z = fmaf(pr2.w, v3.z, A2.z); A2.w = fmaf(pr2.w, v3.w, A2.w);
      A3.x = fmaf(pr3.x, v0.x, A3.x); A3.y = fmaf(pr3.x, v0.y, A3.y);
      A3.z = fmaf(pr3.x, v0.z, A3.z); A3.w = fmaf(pr3.x, v0.w, A3.w);
      A3.x = fmaf(pr3.y, v1.x, A3.x); A3.y = fmaf(pr3.y, v1.y, A3.y);
      A3.z = fmaf(pr3.y, v1.z, A3.z); A3.w = fmaf(pr3.y, v1.w, A3.w);
      A3.x = fmaf(pr3.z, v2.x, A3.x); A3.y = fmaf(pr3.z, v2.y, A3.y);
      A3.z = fmaf(pr3.z, v2.z, A3.z); A3.w = fmaf(pr3.z, v2.w, A3.w);
      A3.x = fmaf(pr3.w, v3.x, A3.x); A3.y = fmaf(pr3.w, v3.y, A3.y);
      A3.z = fmaf(pr3.w, v3.z, A3.z); A3.w = fmaf(pr3.w, v3.w, A3.w);
    }
    pa[0] = A0; pa[1] = A1; pa[2] = A2; pa[3] = A3;
  }
  __syncthreads();  // all score reads complete; safe to reuse LDS
  {
    const int cq = t & 127, ph = t >> 7;
    float* parts = &scoresS[0][0];  // [4 q][4 ph][128 cq][4] = 32 KB alias
#pragma unroll
    for (int qi = 0; qi < 4; ++qi)
      *(float4*)&parts[((qi * 4 + ph) * 128 + cq) * 4] = pa[qi];
  }
  __syncthreads();
  {
    const int q = t >> 7, c = t & 127;  // 512 threads = 4q x 128c
    const float* parts = &scoresS[0][0];
    float4 a = *(const float4*)&parts[((q * 4 + 0) * 128 + c) * 4];
#pragma unroll
    for (int ph = 1; ph < 4; ++ph) {
      float4 x = *(const float4*)&parts[((q * 4 + ph) * 128 + c) * 4];
      a.x += x.x; a.y += x.y; a.z += x.z; a.w += x.w;
    }
    *(float4*)&AO[(size_t)(bl0 + q) * 512 + 4 * c] = a;
  }
}

// ---------------------------------------------------------------------------
// Output projection + residual: Xout = AO@Wo + bo + query   (fp32 ws)
// ---------------------------------------------------------------------------
__global__ __launch_bounds__(256) void proj_out(
    const float* __restrict__ X, const void* __restrict__ W,
    const void* __restrict__ bias, const void* __restrict__ resid,
    float* __restrict__ Y, const int* __restrict__ flag) {
  __shared__ float As[16][64];
  __shared__ float Bs[16][64];
  const bool f32 = (*flag != 0);
  const int bm = blockIdx.x * 64, bn = blockIdx.y * 64;
  const int tid = threadIdx.x;
  const int tx = tid & 15, ty = tid >> 4;
  float acc[4][4] = {};
  for (int k0 = 0; k0 < 512; k0 += 16) {
    {
      int r = tid >> 2, kf = (tid & 3) * 4;
      float4 x4 = *(const float4*)(X + (size_t)(bm + r) * 512 + k0 + kf);
      As[kf + 0][r] = x4.x; As[kf + 1][r] = x4.y;
      As[kf + 2][r] = x4.z; As[kf + 3][r] = x4.w;
    }
    if (f32) {
      int kk = tid >> 4, cf = (tid & 15) * 4;
      *(float4*)&Bs[kk][cf] =
          *(const float4*)((const float*)W + (size_t)(k0 + kk) * 512 + bn + cf);
    } else {
      const unsigned short* Wb = (const unsigned short*)W;
      for (int f = tid; f < 16 * 64; f += 256) {
        int kk = f >> 6, c = f & 63;
        Bs[kk][c] = bf2f(Wb[(size_t)(k0 + kk) * 512 + bn + c]);
      }
    }
    __syncthreads();
#pragma unroll
    for (int k = 0; k < 16; ++k) {
      float4 a4 = *(const float4*)&As[k][ty * 4];
      float4 b4 = *(const float4*)&Bs[k][tx * 4];
      acc[0][0] = fmaf(a4.x, b4.x, acc[0][0]); acc[0][1] = fmaf(a4.x, b4.y, acc[0][1]);
      acc[0][2] = fmaf(a4.x, b4.z, acc[0][2]); acc[0][3] = fmaf(a4.x, b4.w, acc[0][3]);
      acc[1][0] = fmaf(a4.y, b4.x, acc[1][0]); acc[1][1] = fmaf(a4.y, b4.y, acc[1][1]);
      acc[1][2] = fmaf(a4.y, b4.z, acc[1][2]); acc[1][3] = fmaf(a4.y, b4.w, acc[1][3]);
      acc[2][0] = fmaf(a4.z, b4.x, acc[2][0]); acc[2][1] = fmaf(a4.z, b4.y, acc[2][1]);
      acc[2][2] = fmaf(a4.z, b4.z, acc[2][2]); acc[2][3] = fmaf(a4.z, b4.w, acc[2][3]);
      acc[3][0] = fmaf(a4.w, b4.x, acc[3][0]); acc[3][1] = fmaf(a4.w, b4.y, acc[3][1]);
      acc[3][2] = fmaf(a4.w, b4.z, acc[3][2]); acc[3][3] = fmaf(a4.w, b4.w, acc[3][3]);
    }
    __syncthreads();
  }
#pragma unroll
  for (int i = 0; i < 4; ++i) {
    int r = bm + ty * 4 + i;
    float4 o;
#pragma unroll
    for (int j = 0; j < 4; ++j) {
      int c = bn + tx * 4 + j;
      float v = acc[i][j] + ldf(bias, c, f32) +
                ldf(resid, (size_t)r * 512 + c, f32);
      ((float*)&o)[j] = v;
    }
    *(float4*)(Y + (size_t)r * 512 + bn + tx * 4) = o;
  }
}

// ---------------------------------------------------------------------------
// LayerNorm rows of Xw -> out0
// ---------------------------------------------------------------------------
__global__ __launch_bounds__(256) void ln_kernel(
    const float* __restrict__ Xw, const void* __restrict__ gamma,
    const void* __restrict__ beta, void* __restrict__ d_out,
    const int* __restrict__ flag) {
  const int bl = blockIdx.x;
  const int tid = threadIdx.x;
  const bool f32 = (*flag != 0);
  __shared__ float red[16];
  float v0 = Xw[(size_t)bl * 512 + tid];
  float v1 = Xw[(size_t)bl * 512 + tid + 256];
  float s = v0 + v1, s2 = v0 * v0 + v1 * v1;
#pragma unroll
  for (int off = 32; off; off >>= 1) {
    s += __shfl_xor(s, off, 64);
    s2 += __shfl_xor(s2, off, 64);
  }
  const int wave = tid >> 6, lane = tid & 63;
  if (lane == 0) { red[wave] = s; red[8 + wave] = s2; }
  __syncthreads();
  if (tid == 0) {
    float ts = 0.f, ts2 = 0.f;
    for (int w = 0; w < 4; ++w) { ts += red[w]; ts2 += red[8 + w]; }
    red[0] = ts; red[1] = ts2;
  }
  __syncthreads();
  const float mu = red[0] * (1.0f / 512.0f);
  const float var = red[1] * (1.0f / 512.0f) - mu * mu;
  const float rstd = rsqrtf(var + 1e-5f);
  float o0 = (v0 - mu) * rstd * ldf(gamma, tid, f32) + ldf(beta, tid, f32);
  float o1 = (v1 - mu) * rstd * ldf(gamma, tid + 256, f32) +
             ldf(beta, tid + 256, f32);
  if (f32) {
    float* o = (float*)d_out;
    o[(size_t)bl * 512 + tid] = o0;
    o[(size_t)bl * 512 + tid + 256] = o1;
  } else {
    __hip_bfloat16* o = (__hip_bfloat16*)d_out;
    o[(size_t)bl * 512 + tid] = __float2bfloat16(o0);
    o[(size_t)bl * 512 + tid + 256] = __float2bfloat16(o1);
  }
}

// ---------------------------------------------------------------------------
extern "C" void kernel_launch(void* const* d_in, const int* in_sizes, int n_in,
                              void* d_out, int out_size, void* d_ws,
                              size_t ws_size, hipStream_t stream) {
  const void* query = d_in[0];
  const void* key = d_in[1];
  const void* value = d_in[2];
  const void* rbf = d_in[3];
  const int* key_mask = (const int*)d_in[4];
  const void* Wq = d_in[5];
  const void* bq = d_in[6];
  const void* Wk = d_in[7];
  const void* bk = d_in[8];
  const void* Wv = d_in[9];
  const void* bv = d_in[10];
  const void* Wr = d_in[11];
  const void* br = d_in[12];
  const void* Wo = d_in[13];
  const void* bo = d_in[14];
  const void* gamma = d_in[15];
  const void* beta = d_in[16];

  // ws: [flag 16B] Q | Kt | V | AO | X
  int* flag = (int*)d_ws;
  float* base = (float*)d_ws + 4;
  float* Qw = base;
  float* Ktw = Qw + (size_t)BB * LL * DD;   // +524288
  float* Vw = Ktw + (size_t)BB * PP * DD;   // +2097152
  float* AO = Vw + (size_t)BB * PP * DD;    // +2097152
  float* Xw = AO + (size_t)BB * LL * DD;    // +524288

  detect_dtype<<<1, 256, 0, stream>>>((const float*)query, flag);
  qkv_gemm<<<dim3(288), 256, 0, stream>>>(query, key, value, Wq, bq, Wk, bk,
                                          Wv, bv, Qw, Ktw, Vw, flag);
  attn_v10<<<dim3(BB * LL / 4), 512, 0, stream>>>(Qw, Ktw, Vw, rbf, Wr, br,
                                                  key_mask, AO, d_out, flag);
  proj_out<<<dim3(16, 8), 256, 0, stream>>>(AO, Wo, bo, query, Xw, flag);
  ln_kernel<<<dim3(BB * LL), 256, 0, stream>>>(Xw, gamma, beta, d_out, flag);
}

// Round 8
// 529.921 us; speedup vs baseline: 1.8229x; 1.1502x over previous
//
#include <hip/hip_runtime.h>
#include <hip/hip_bf16.h>

#define BB 4
#define LL 256
#define PP 1024
#define DD 512
#define HH 8
#define HD 64
#define NRBF 50

// ---------------------------------------------------------------------------
// dtype helpers (inputs are fp32 per reference; bf16 fallback kept for safety)
// ---------------------------------------------------------------------------
__device__ __forceinline__ float bf2f(unsigned short u) {
  return __uint_as_float((unsigned)u << 16);
}

__device__ __forceinline__ float ldf(const void* p, size_t i, bool f32) {
  if (f32) return ((const float*)p)[i];
  return bf2f(((const unsigned short*)p)[i]);
}

__device__ __forceinline__ float4 ld4e(const void* p, size_t i, bool f32) {
  if (f32) return *(const float4*)((const float*)p + i);
  ushort4 u = *(const ushort4*)((const unsigned short*)p + i);
  float4 r;
  r.x = bf2f(u.x); r.y = bf2f(u.y); r.z = bf2f(u.z); r.w = bf2f(u.w);
  return r;
}

__global__ __launch_bounds__(256) void detect_dtype(const float* q, int* flag) {
  __shared__ int cnt;
  if (threadIdx.x == 0) cnt = 0;
  __syncthreads();
  int c = 0;
  for (int i = threadIdx.x; i < 1024; i += 256) {
    unsigned u = __float_as_uint(q[i]);
    unsigned e = (u >> 23) & 0xffu;
    if (e >= 104u && e <= 140u) c++;
  }
  atomicAdd(&cnt, c);
  __syncthreads();
  if (threadIdx.x == 0) *flag = (cnt > 512) ? 1 : 0;
}

// ---------------------------------------------------------------------------
// 128x64-tile fp32 GEMM, 8x4 per thread, double-buffered, 24 KB LDS.
// 576 blocks -> ~3 resident blocks/CU (vs old 128x128: 288 blocks, 1
// wave/SIMD, VALUBusy 30%). mode 0: row-major out; mode 1: Kt[b][h][d][p].
// LDS layout: As[2][16][128] = lds[0..4095], Bs[2][16][64] = lds[4096..6143]
// ---------------------------------------------------------------------------
__device__ void gemm128x64(const void* __restrict__ X,
                           const void* __restrict__ W,
                           const void* __restrict__ bias,
                           float* __restrict__ Y, const int bm, const int bn,
                           const int mode, const bool f32, float* lds) {
  const int tid = threadIdx.x;
  const int tx = tid & 15, ty = tid >> 4;
  const int lr = tid >> 1, lc = (tid & 1) * 8;   // A staging: row, k0
  const int wk = tid >> 4, wc = (tid & 15) * 4;  // B staging: k-row, col
  float acc[8][4] = {};
  float4 ra0, ra1, rb0;

  ra0 = ld4e(X, (size_t)(bm + lr) * 512 + lc, f32);
  ra1 = ld4e(X, (size_t)(bm + lr) * 512 + lc + 4, f32);
  rb0 = ld4e(W, (size_t)wk * 512 + bn + wc, f32);
  {
    float* Ab = lds;
    float* Bb = lds + 4096;
    Ab[(lc + 0) * 128 + lr] = ra0.x; Ab[(lc + 1) * 128 + lr] = ra0.y;
    Ab[(lc + 2) * 128 + lr] = ra0.z; Ab[(lc + 3) * 128 + lr] = ra0.w;
    Ab[(lc + 4) * 128 + lr] = ra1.x; Ab[(lc + 5) * 128 + lr] = ra1.y;
    Ab[(lc + 6) * 128 + lr] = ra1.z; Ab[(lc + 7) * 128 + lr] = ra1.w;
    *(float4*)&Bb[wk * 64 + wc] = rb0;
  }
  __syncthreads();

  int buf = 0;
  for (int tt = 0; tt < 32; ++tt) {
    if (tt < 31) {
      const int k0 = (tt + 1) * 16;
      ra0 = ld4e(X, (size_t)(bm + lr) * 512 + k0 + lc, f32);
      ra1 = ld4e(X, (size_t)(bm + lr) * 512 + k0 + lc + 4, f32);
      rb0 = ld4e(W, (size_t)(k0 + wk) * 512 + bn + wc, f32);
    }
    {
      const float* Ab = lds + buf * 2048;
      const float* Bb = lds + 4096 + buf * 1024;
#pragma unroll
      for (int k = 0; k < 16; ++k) {
        float4 aL = *(const float4*)&Ab[k * 128 + ty * 4];
        float4 aH = *(const float4*)&Ab[k * 128 + 64 + ty * 4];
        float4 b4 = *(const float4*)&Bb[k * 64 + tx * 4];
        const float a8[8] = {aL.x, aL.y, aL.z, aL.w, aH.x, aH.y, aH.z, aH.w};
#pragma unroll
        for (int i = 0; i < 8; ++i) {
          acc[i][0] = fmaf(a8[i], b4.x, acc[i][0]);
          acc[i][1] = fmaf(a8[i], b4.y, acc[i][1]);
          acc[i][2] = fmaf(a8[i], b4.z, acc[i][2]);
          acc[i][3] = fmaf(a8[i], b4.w, acc[i][3]);
        }
      }
    }
    if (tt < 31) {
      float* Ab = lds + (buf ^ 1) * 2048;
      float* Bb = lds + 4096 + (buf ^ 1) * 1024;
      Ab[(lc + 0) * 128 + lr] = ra0.x; Ab[(lc + 1) * 128 + lr] = ra0.y;
      Ab[(lc + 2) * 128 + lr] = ra0.z; Ab[(lc + 3) * 128 + lr] = ra0.w;
      Ab[(lc + 4) * 128 + lr] = ra1.x; Ab[(lc + 5) * 128 + lr] = ra1.y;
      Ab[(lc + 6) * 128 + lr] = ra1.z; Ab[(lc + 7) * 128 + lr] = ra1.w;
      *(float4*)&Bb[wk * 64 + wc] = rb0;
    }
    __syncthreads();
    buf ^= 1;
  }

  if (mode == 0) {
#pragma unroll
    for (int rh = 0; rh < 2; ++rh)
#pragma unroll
      for (int i = 0; i < 4; ++i) {
        const int r = bm + rh * 64 + ty * 4 + i;
        const int c = bn + tx * 4;
        float4 o;
        o.x = acc[rh * 4 + i][0] + ldf(bias, c + 0, f32);
        o.y = acc[rh * 4 + i][1] + ldf(bias, c + 1, f32);
        o.z = acc[rh * 4 + i][2] + ldf(bias, c + 2, f32);
        o.w = acc[rh * 4 + i][3] + ldf(bias, c + 3, f32);
        *(float4*)&Y[(size_t)r * 512 + c] = o;
      }
  } else {
    const int bq = bm >> 10;
    const int pb = bm & 1023;
    const int h = bn >> 6;  // bn is a multiple of 64 -> single head per tile
#pragma unroll
    for (int j = 0; j < 4; ++j) {
      const int c = bn + tx * 4 + j;
      const int d = c & 63;
      const float bb = ldf(bias, c, f32);
#pragma unroll
      for (int rh = 0; rh < 2; ++rh) {
        float4 pv;
        pv.x = acc[rh * 4 + 0][j] + bb;
        pv.y = acc[rh * 4 + 1][j] + bb;
        pv.z = acc[rh * 4 + 2][j] + bb;
        pv.w = acc[rh * 4 + 3][j] + bb;
        const int p0 = pb + rh * 64 + ty * 4;
        *(float4*)&Y[(((size_t)bq * 8 + h) * 64 + d) * 1024 + p0] = pv;
      }
    }
  }
}

// ---------------------------------------------------------------------------
// Q/K/V projections. blocks 0..63: Q (M=1024); 64..319: K (mode 1);
// 320..575: V. 576 blocks total.
// ---------------------------------------------------------------------------
__global__ __launch_bounds__(256, 3) void qkv_gemm(
    const void* __restrict__ query, const void* __restrict__ key,
    const void* __restrict__ value, const void* __restrict__ Wq,
    const void* __restrict__ bq_, const void* __restrict__ Wk,
    const void* __restrict__ bk_, const void* __restrict__ Wv,
    const void* __restrict__ bv_, float* __restrict__ Qw,
    float* __restrict__ Ktw, float* __restrict__ Vw,
    const int* __restrict__ flag) {
  __shared__ float lds[6144];  // 24 KB
  const bool f32 = (*flag != 0);
  const int blk = blockIdx.x;

  const void *X, *W, *bias;
  float* Y;
  int mode, mi, ni;
  if (blk < 64) {
    X = query; W = Wq; bias = bq_; Y = Qw; mode = 0;
    mi = blk >> 3; ni = blk & 7;
  } else if (blk < 320) {
    const int q2 = blk - 64;
    X = key; W = Wk; bias = bk_; Y = Ktw; mode = 1;
    mi = q2 >> 3; ni = q2 & 7;
  } else {
    const int q2 = blk - 320;
    X = value; W = Wv; bias = bv_; Y = Vw; mode = 0;
    mi = q2 >> 3; ni = q2 & 7;
  }
  gemm128x64(X, W, bias, Y, mi * 128, ni * 64, mode, f32, lds);
}

// ---------------------------------------------------------------------------
// Attention v10 (unchanged from round 7): 4 queries/block, 256 blocks.
// ---------------------------------------------------------------------------
#define SST 1028  // padded score stride

__global__ __launch_bounds__(512) void attn_v10(
    const float* __restrict__ Q,     // [B*L, 512]
    const float* __restrict__ Kt,    // [B][8][64][1024]
    const float* __restrict__ V,     // [B*P, 512]
    const void* __restrict__ rbf,    // [B*L*P, 50]
    const void* __restrict__ Wr,     // [50, 8]
    const void* __restrict__ br_,    // [8]
    const int* __restrict__ mask,    // [B,P]
    float* __restrict__ AO,          // [B*L, 512]
    void* __restrict__ d_out, const int* __restrict__ flag) {
  const int xcd = blockIdx.x & 7;
  const int idx = blockIdx.x >> 3;          // 0..31
  const int b = xcd >> 1;
  const int lq = ((xcd & 1) << 5) | idx;    // 0..63
  const int bl0 = b * LL + lq * 4;          // first of 4 queries
  const int t = threadIdx.x;
  const bool f32 = (*flag != 0);

  __shared__ float qS[4][512];              // 8 KB
  __shared__ float wrS[NRBF * 8];           // 1.6 KB
  __shared__ float brS[8];
  __shared__ float scoresS[4][8 * SST];     // 131.6 KB

  for (int i = t; i < 2048; i += 512)
    qS[i >> 9][i & 511] = Q[(size_t)bl0 * 512 + i];
  for (int i = t; i < NRBF * 8; i += 512) wrS[i] = ldf(Wr, i, f32);
  if (t < 8) brS[t] = ldf(br_, t, f32);
  __syncthreads();

  // ---- phase A: rbf bias -> scoresS ----
  {
    const int qh = t >> 8;
    const int tq = t & 255;
#pragma unroll
    for (int qi = 0; qi < 2; ++qi) {
      const int q = qh * 2 + qi;
      float acc[4][8];
#pragma unroll
      for (int e = 0; e < 4; ++e)
#pragma unroll
        for (int h = 0; h < 8; ++h) acc[e][h] = brS[h];
      const size_t rbase = ((size_t)(bl0 + q) * 1024 + 4 * tq) * NRBF;
      if (f32) {
        const float* rowb = (const float*)rbf + rbase;
#pragma unroll
        for (int e = 0; e < 4; ++e) {
          const float2* rp = (const float2*)(rowb + e * NRBF);  // 8-B aligned
#pragma unroll 5
          for (int j = 0; j < 25; ++j) {
            const float2 r2 = rp[j];
            const float4 wa = *(const float4*)&wrS[(2 * j) * 8];
            const float4 wb = *(const float4*)&wrS[(2 * j) * 8 + 4];
            const float4 wc = *(const float4*)&wrS[(2 * j + 1) * 8];
            const float4 wd = *(const float4*)&wrS[(2 * j + 1) * 8 + 4];
            acc[e][0] = fmaf(r2.x, wa.x, acc[e][0]);
            acc[e][1] = fmaf(r2.x, wa.y, acc[e][1]);
            acc[e][2] = fmaf(r2.x, wa.z, acc[e][2]);
            acc[e][3] = fmaf(r2.x, wa.w, acc[e][3]);
            acc[e][4] = fmaf(r2.x, wb.x, acc[e][4]);
            acc[e][5] = fmaf(r2.x, wb.y, acc[e][5]);
            acc[e][6] = fmaf(r2.x, wb.z, acc[e][6]);
            acc[e][7] = fmaf(r2.x, wb.w, acc[e][7]);
            acc[e][0] = fmaf(r2.y, wc.x, acc[e][0]);
            acc[e][1] = fmaf(r2.y, wc.y, acc[e][1]);
            acc[e][2] = fmaf(r2.y, wc.z, acc[e][2]);
            acc[e][3] = fmaf(r2.y, wc.w, acc[e][3]);
            acc[e][4] = fmaf(r2.y, wd.x, acc[e][4]);
            acc[e][5] = fmaf(r2.y, wd.y, acc[e][5]);
            acc[e][6] = fmaf(r2.y, wd.z, acc[e][6]);
            acc[e][7] = fmaf(r2.y, wd.w, acc[e][7]);
          }
        }
      } else {
        const unsigned short* rb = (const unsigned short*)rbf + rbase;
#pragma unroll
        for (int e = 0; e < 4; ++e) {
#pragma unroll 1
          for (int j = 0; j < 50; ++j) {
            const float rv = bf2f(rb[e * 50 + j]);
#pragma unroll
            for (int h = 0; h < 8; ++h)
              acc[e][h] = fmaf(rv, wrS[j * 8 + h], acc[e][h]);
          }
        }
      }
#pragma unroll
      for (int h = 0; h < 8; ++h) {
        float4 o;
        o.x = acc[0][h]; o.y = acc[1][h]; o.z = acc[2][h]; o.w = acc[3][h];
        *(float4*)&scoresS[q][h * SST + 4 * tq] = o;
      }
    }
  }
  __syncthreads();

  // ---- phase B: scores = bias + 0.125*QK^T; one Kt read serves 4 q ----
  {
    const int tq = t & 255;
    const int hh = t >> 8;
    const int4 mk4 = *(const int4*)(mask + b * PP + 4 * tq);
#pragma unroll 1
    for (int hi = 0; hi < 4; ++hi) {
      const int h = hh * 4 + hi;
      const float4* ktp =
          (const float4*)(Kt + ((size_t)b * 8 + h) * 64 * 1024) + tq;
      float4 a0 = {0.f, 0.f, 0.f, 0.f}, a1 = {0.f, 0.f, 0.f, 0.f};
      float4 a2 = {0.f, 0.f, 0.f, 0.f}, a3 = {0.f, 0.f, 0.f, 0.f};
#pragma unroll 2
      for (int dq = 0; dq < 16; ++dq) {
        float4 q0 = *(const float4*)&qS[0][h * 64 + dq * 4];  // bcast
        float4 q1 = *(const float4*)&qS[1][h * 64 + dq * 4];
        float4 q2 = *(const float4*)&qS[2][h * 64 + dq * 4];
        float4 q3 = *(const float4*)&qS[3][h * 64 + dq * 4];
        float4 k0 = ktp[(size_t)(dq * 4 + 0) * 256];
        float4 k1 = ktp[(size_t)(dq * 4 + 1) * 256];
        float4 k2 = ktp[(size_t)(dq * 4 + 2) * 256];
        float4 k3 = ktp[(size_t)(dq * 4 + 3) * 256];
        a0.x = fmaf(q0.x, k0.x, a0.x); a0.y = fmaf(q0.x, k0.y, a0.y);
        a0.z = fmaf(q0.x, k0.z, a0.z); a0.w = fmaf(q0.x, k0.w, a0.w);
        a0.x = fmaf(q0.y, k1.x, a0.x); a0.y = fmaf(q0.y, k1.y, a0.y);
        a0.z = fmaf(q0.y, k1.z, a0.z); a0.w = fmaf(q0.y, k1.w, a0.w);
        a0.x = fmaf(q0.z, k2.x, a0.x); a0.y = fmaf(q0.z, k2.y, a0.y);
        a0.z = fmaf(q0.z, k2.z, a0.z); a0.w = fmaf(q0.z, k2.w, a0.w);
        a0.x = fmaf(q0.w, k3.x, a0.x); a0.y = fmaf(q0.w, k3.y, a0.y);
        a0.z = fmaf(q0.w, k3.z, a0.z); a0.w = fmaf(q0.w, k3.w, a0.w);
        a1.x = fmaf(q1.x, k0.x, a1.x); a1.y = fmaf(q1.x, k0.y, a1.y);
        a1.z = fmaf(q1.x, k0.z, a1.z); a1.w = fmaf(q1.x, k0.w, a1.w);
        a1.x = fmaf(q1.y, k1.x, a1.x); a1.y = fmaf(q1.y, k1.y, a1.y);
        a1.z = fmaf(q1.y, k1.z, a1.z); a1.w = fmaf(q1.y, k1.w, a1.w);
        a1.x = fmaf(q1.z, k2.x, a1.x); a1.y = fmaf(q1.z, k2.y, a1.y);
        a1.z = fmaf(q1.z, k2.z, a1.z); a1.w = fmaf(q1.z, k2.w, a1.w);
        a1.x = fmaf(q1.w, k3.x, a1.x); a1.y = fmaf(q1.w, k3.y, a1.y);
        a1.z = fmaf(q1.w, k3.z, a1.z); a1.w = fmaf(q1.w, k3.w, a1.w);
        a2.x = fmaf(q2.x, k0.x, a2.x); a2.y = fmaf(q2.x, k0.y, a2.y);
        a2.z = fmaf(q2.x, k0.z, a2.z); a2.w = fmaf(q2.x, k0.w, a2.w);
        a2.x = fmaf(q2.y, k1.x, a2.x); a2.y = fmaf(q2.y, k1.y, a2.y);
        a2.z = fmaf(q2.y, k1.z, a2.z); a2.w = fmaf(q2.y, k1.w, a2.w);
        a2.x = fmaf(q2.z, k2.x, a2.x); a2.y = fmaf(q2.z, k2.y, a2.y);
        a2.z = fmaf(q2.z, k2.z, a2.z); a2.w = fmaf(q2.z, k2.w, a2.w);
        a2.x = fmaf(q2.w, k3.x, a2.x); a2.y = fmaf(q2.w, k3.y, a2.y);
        a2.z = fmaf(q2.w, k3.z, a2.z); a2.w = fmaf(q2.w, k3.w, a2.w);
        a3.x = fmaf(q3.x, k0.x, a3.x); a3.y = fmaf(q3.x, k0.y, a3.y);
        a3.z = fmaf(q3.x, k0.z, a3.z); a3.w = fmaf(q3.x, k0.w, a3.w);
        a3.x = fmaf(q3.y, k1.x, a3.x); a3.y = fmaf(q3.y, k1.y, a3.y);
        a3.z = fmaf(q3.y, k1.z, a3.z); a3.w = fmaf(q3.y, k1.w, a3.w);
        a3.x = fmaf(q3.z, k2.x, a3.x); a3.y = fmaf(q3.z, k2.y, a3.y);
        a3.z = fmaf(q3.z, k2.z, a3.z); a3.w = fmaf(q3.z, k2.w, a3.w);
        a3.x = fmaf(q3.w, k3.x, a3.x); a3.y = fmaf(q3.w, k3.y, a3.y);
        a3.z = fmaf(q3.w, k3.z, a3.z); a3.w = fmaf(q3.w, k3.w, a3.w);
      }
      float4 av[4] = {a0, a1, a2, a3};
#pragma unroll
      for (int qi = 0; qi < 4; ++qi) {
        float4 bq4 = *(const float4*)&scoresS[qi][h * SST + 4 * tq];
        float4 s;
        s.x = (mk4.x == 0) ? -1e9f : fmaf(av[qi].x, 0.125f, bq4.x);
        s.y = (mk4.y == 0) ? -1e9f : fmaf(av[qi].y, 0.125f, bq4.y);
        s.z = (mk4.z == 0) ? -1e9f : fmaf(av[qi].z, 0.125f, bq4.z);
        s.w = (mk4.w == 0) ? -1e9f : fmaf(av[qi].w, 0.125f, bq4.w);
        *(float4*)&scoresS[qi][h * SST + 4 * tq] = s;
      }
    }
  }
  __syncthreads();

  // ---- softmax over P: 32 (q,h) rows, 4 per wave ----
  {
    const int wave = t >> 6, lane = t & 63;
    for (int pr = wave * 4; pr < wave * 4 + 4; ++pr) {
      float* sc = &scoresS[pr >> 3][(pr & 7) * SST];
      float m = -3.0e38f;
      for (int i = lane; i < PP; i += 64) m = fmaxf(m, sc[i]);
#pragma unroll
      for (int off = 32; off; off >>= 1) m = fmaxf(m, __shfl_xor(m, off, 64));
      float sum = 0.f;
      for (int i = lane; i < PP; i += 64) {
        float e = __expf(sc[i] - m);
        sc[i] = e;
        sum += e;
      }
#pragma unroll
      for (int off = 32; off; off >>= 1) sum += __shfl_xor(sum, off, 64);
      const float inv = 1.0f / sum;
      for (int i = lane; i < PP; i += 64) sc[i] *= inv;
    }
  }
  __syncthreads();

  // ---- attn_mean ----
  for (int w = t; w < 1024; w += 512) {
    const int q = w >> 8, pq = w & 255;
    float4 s = {0.f, 0.f, 0.f, 0.f};
#pragma unroll
    for (int h = 0; h < 8; ++h) {
      float4 v = *(const float4*)&scoresS[q][h * SST + 4 * pq];
      s.x += v.x; s.y += v.y; s.z += v.z; s.w += v.w;
    }
    s.x *= 0.125f; s.y *= 0.125f; s.z *= 0.125f; s.w *= 0.125f;
    const size_t base =
        (size_t)BB * LL * DD + (size_t)(bl0 + q) * PP + 4 * pq;
    if (f32) {
      *(float4*)((float*)d_out + base) = s;
    } else {
      __hip_bfloat16* o1 = (__hip_bfloat16*)d_out;
      o1[base + 0] = __float2bfloat16(s.x);
      o1[base + 1] = __float2bfloat16(s.y);
      o1[base + 2] = __float2bfloat16(s.z);
      o1[base + 3] = __float2bfloat16(s.w);
    }
  }

  // ---- PV ----
  float4 pa[4];
  {
    const int cq = t & 127;
    const int ph = t >> 7;
    const int h = cq >> 4;
    const float* sc0 = &scoresS[0][h * SST];
    const float* sc1 = &scoresS[1][h * SST];
    const float* sc2 = &scoresS[2][h * SST];
    const float* sc3 = &scoresS[3][h * SST];
    const float4* Vb = (const float4*)(V + (size_t)b * PP * 512) + cq;
    float4 A0 = {0.f, 0.f, 0.f, 0.f}, A1 = {0.f, 0.f, 0.f, 0.f};
    float4 A2 = {0.f, 0.f, 0.f, 0.f}, A3 = {0.f, 0.f, 0.f, 0.f};
    const int p0 = ph * 256;
#pragma unroll 2
    for (int p4 = p0; p4 < p0 + 256; p4 += 4) {
      float4 pr0 = *(const float4*)&sc0[p4];
      float4 pr1 = *(const float4*)&sc1[p4];
      float4 pr2 = *(const float4*)&sc2[p4];
      float4 pr3 = *(const float4*)&sc3[p4];
      float4 v0 = Vb[(size_t)(p4 + 0) * 128];
      float4 v1 = Vb[(size_t)(p4 + 1) * 128];
      float4 v2 = Vb[(size_t)(p4 + 2) * 128];
      float4 v3 = Vb[(size_t)(p4 + 3) * 128];
      A0.x = fmaf(pr0.x, v0.x, A0.x); A0.y = fmaf(pr0.x, v0.y, A0.y);
      A0.z = fmaf(pr0.x, v0.z, A0.z); A0.w = fmaf(pr0.x, v0.w, A0.w);
      A0.x = fmaf(pr0.y, v1.x, A0.x); A0.y = fmaf(pr0.y, v1.y, A0.y);
      A0.z = fmaf(pr0.y, v1.z, A0.z); A0.w = fmaf(pr0.y, v1.w, A0.w);
      A0.x = fmaf(pr0.z, v2.x, A0.x); A0.y = fmaf(pr0.z, v2.y, A0.y);
      A0.z = fmaf(pr0.z, v2.z, A0.z); A0.w = fmaf(pr0.z, v2.w, A0.w);
      A0.x = fmaf(pr0.w, v3.x, A0.x); A0.y = fmaf(pr0.w, v3.y, A0.y);
      A0.z = fmaf(pr0.w, v3.z, A0.z); A0.w = fmaf(pr0.w, v3.w, A0.w);
      A1.x = fmaf(pr1.x, v0.x, A1.x); A1.y = fmaf(pr1.x, v0.y, A1.y);
      A1.z = fmaf(pr1.x, v0.z, A1.z); A1.w = fmaf(pr1.x, v0.w, A1.w);
      A1.x = fmaf(pr1.y, v1.x, A1.x); A1.y = fmaf(pr1.y, v1.y, A1.y);
      A1.z = fmaf(pr1.y, v1.z, A1.z); A1.w = fmaf(pr1.y, v1.w, A1.w);
      A1.x = fmaf(pr1.z, v2.x, A1.x); A1.y = fmaf(pr1.z, v2.y, A1.y);
      A1.z = fmaf(pr1.z, v2.z, A1.z); A1.w = fmaf(pr1.z, v2.w, A1.w);
      A1.x = fmaf(pr1.w, v3.x, A1.x); A1.y = fmaf(pr1.w, v3.y, A1.y);
      A1.z = fmaf(pr1.w, v3.z, A1.z); A1.w = fmaf(pr1.w, v3.w, A1.w);
      A2.x = fmaf(pr2.x, v0.x, A2.x); A2.y = fmaf(pr2.x, v0.y, A2.y);
      A2.z = fmaf(pr2.x, v0.z, A2.z); A2.w = fmaf(pr2.x, v0.w, A2.w);
      A2.x = fmaf(pr2.y, v1.x, A2.x); A2.y = fmaf(pr2.y, v1.y, A2.y);
      A2.z = fmaf(pr2.y, v1.z, A2.z); A2.w = fmaf(pr2.y, v1.w, A2.w);
      A2.x = fmaf(pr2.z, v2.x, A2.x); A2.y = fmaf(pr2.z, v2.y, A2.y);
      A2.z = fmaf(pr2.z, v2.z, A2.z); A2.w = fmaf(pr2.z, v2.w, A2.w);
      A2.x = fmaf(pr2.w, v3.x, A2.x); A2.y = fmaf(pr2.w, v3.y, A2.y);
      A2.z = fmaf(pr2.w, v3.z, A2.z); A2.w = fmaf(pr2.w, v3.w, A2.w);
      A3.x = fmaf(pr3.x, v0.x, A3.x); A3.y = fmaf(pr3.x, v0.y, A3.y);
      A3.z = fmaf(pr3.x, v0.z, A3.z); A3.w = fmaf(pr3.x, v0.w, A3.w);
      A3.x = fmaf(pr3.y, v1.x, A3.x); A3.y = fmaf(pr3.y, v1.y, A3.y);
      A3.z = fmaf(pr3.y, v1.z, A3.z); A3.w = fmaf(pr3.y, v1.w, A3.w);
      A3.x = fmaf(pr3.z, v2.x, A3.x); A3.y = fmaf(pr3.z, v2.y, A3.y);
      A3.z = fmaf(pr3.z, v2.z, A3.z); A3.w = fmaf(pr3.z, v2.w, A3.w);
      A3.x = fmaf(pr3.w, v3.x, A3.x); A3.y = fmaf(pr3.w, v3.y, A3.y);
      A3.z = fmaf(pr3.w, v3.z, A3.z); A3.w = fmaf(pr3.w, v3.w, A3.w);
    }
    pa[0] = A0; pa[1] = A1; pa[2] = A2; pa[3] = A3;
  }
  __syncthreads();
  {
    const int cq = t & 127, ph = t >> 7;
    float* parts = &scoresS[0][0];
#pragma unroll
    for (int qi = 0; qi < 4; ++qi)
      *(float4*)&parts[((qi * 4 + ph) * 128 + cq) * 4] = pa[qi];
  }
  __syncthreads();
  {
    const int q = t >> 7, c = t & 127;
    const float* parts = &scoresS[0][0];
    float4 a = *(const float4*)&parts[((q * 4 + 0) * 128 + c) * 4];
#pragma unroll
    for (int ph = 1; ph < 4; ++ph) {
      float4 x = *(const float4*)&parts[((q * 4 + ph) * 128 + c) * 4];
      a.x += x.x; a.y += x.y; a.z += x.z; a.w += x.w;
    }
    *(float4*)&AO[(size_t)(bl0 + q) * 512 + 4 * c] = a;
  }
}

// ---------------------------------------------------------------------------
// Output projection, split-K x2: each block computes a 64x64 tile over half
// of K, writes partial to Xp[kz]. 256 blocks (was 128, half the GPU idle).
// bias + residual move to ln_kernel.
// ---------------------------------------------------------------------------
__global__ __launch_bounds__(256) void proj_out(
    const float* __restrict__ X, const void* __restrict__ W,
    float* __restrict__ Xp, const int* __restrict__ flag) {
  __shared__ float As[16][64];
  __shared__ float Bs[16][64];
  const bool f32 = (*flag != 0);
  const int bm = blockIdx.x * 64, bn = blockIdx.y * 64;
  const int kz = blockIdx.z;
  const int tid = threadIdx.x;
  const int tx = tid & 15, ty = tid >> 4;
  float acc[4][4] = {};
  const int kbeg = kz * 256;
  for (int k0 = kbeg; k0 < kbeg + 256; k0 += 16) {
    {
      int r = tid >> 2, kf = (tid & 3) * 4;
      float4 x4 = *(const float4*)(X + (size_t)(bm + r) * 512 + k0 + kf);
      As[kf + 0][r] = x4.x; As[kf + 1][r] = x4.y;
      As[kf + 2][r] = x4.z; As[kf + 3][r] = x4.w;
    }
    if (f32) {
      int kk = tid >> 4, cf = (tid & 15) * 4;
      *(float4*)&Bs[kk][cf] =
          *(const float4*)((const float*)W + (size_t)(k0 + kk) * 512 + bn + cf);
    } else {
      const unsigned short* Wb = (const unsigned short*)W;
      for (int f = tid; f < 16 * 64; f += 256) {
        int kk = f >> 6, c = f & 63;
        Bs[kk][c] = bf2f(Wb[(size_t)(k0 + kk) * 512 + bn + c]);
      }
    }
    __syncthreads();
#pragma unroll
    for (int k = 0; k < 16; ++k) {
      float4 a4 = *(const float4*)&As[k][ty * 4];
      float4 b4 = *(const float4*)&Bs[k][tx * 4];
      acc[0][0] = fmaf(a4.x, b4.x, acc[0][0]); acc[0][1] = fmaf(a4.x, b4.y, acc[0][1]);
      acc[0][2] = fmaf(a4.x, b4.z, acc[0][2]); acc[0][3] = fmaf(a4.x, b4.w, acc[0][3]);
      acc[1][0] = fmaf(a4.y, b4.x, acc[1][0]); acc[1][1] = fmaf(a4.y, b4.y, acc[1][1]);
      acc[1][2] = fmaf(a4.y, b4.z, acc[1][2]); acc[1][3] = fmaf(a4.y, b4.w, acc[1][3]);
      acc[2][0] = fmaf(a4.z, b4.x, acc[2][0]); acc[2][1] = fmaf(a4.z, b4.y, acc[2][1]);
      acc[2][2] = fmaf(a4.z, b4.z, acc[2][2]); acc[2][3] = fmaf(a4.z, b4.w, acc[2][3]);
      acc[3][0] = fmaf(a4.w, b4.x, acc[3][0]); acc[3][1] = fmaf(a4.w, b4.y, acc[3][1]);
      acc[3][2] = fmaf(a4.w, b4.z, acc[3][2]); acc[3][3] = fmaf(a4.w, b4.w, acc[3][3]);
    }
    __syncthreads();
  }
  float* Y = Xp + (size_t)kz * BB * LL * DD;
#pragma unroll
  for (int i = 0; i < 4; ++i) {
    int r = bm + ty * 4 + i;
    float4 o;
    o.x = acc[i][0]; o.y = acc[i][1]; o.z = acc[i][2]; o.w = acc[i][3];
    *(float4*)(Y + (size_t)r * 512 + bn + tx * 4) = o;
  }
}

// ---------------------------------------------------------------------------
// LayerNorm: x = Xp0 + Xp1 + bo + query (residual), then LN -> out0
// ---------------------------------------------------------------------------
__global__ __launch_bounds__(256) void ln_kernel(
    const float* __restrict__ Xp, const void* __restrict__ resid,
    const void* __restrict__ bo_, const void* __restrict__ gamma,
    const void* __restrict__ beta, void* __restrict__ d_out,
    const int* __restrict__ flag) {
  const int bl = blockIdx.x;
  const int tid = threadIdx.x;
  const bool f32 = (*flag != 0);
  const size_t half = (size_t)BB * LL * DD;
  __shared__ float red[16];
  const size_t i0 = (size_t)bl * 512 + tid;
  const size_t i1 = i0 + 256;
  float v0 = Xp[i0] + Xp[half + i0] + ldf(bo_, tid, f32) +
             ldf(resid, i0, f32);
  float v1 = Xp[i1] + Xp[half + i1] + ldf(bo_, tid + 256, f32) +
             ldf(resid, i1, f32);
  float s = v0 + v1, s2 = v0 * v0 + v1 * v1;
#pragma unroll
  for (int off = 32; off; off >>= 1) {
    s += __shfl_xor(s, off, 64);
    s2 += __shfl_xor(s2, off, 64);
  }
  const int wave = tid >> 6, lane = tid & 63;
  if (lane == 0) { red[wave] = s; red[8 + wave] = s2; }
  __syncthreads();
  if (tid == 0) {
    float ts = 0.f, ts2 = 0.f;
    for (int w = 0; w < 4; ++w) { ts += red[w]; ts2 += red[8 + w]; }
    red[0] = ts; red[1] = ts2;
  }
  __syncthreads();
  const float mu = red[0] * (1.0f / 512.0f);
  const float var = red[1] * (1.0f / 512.0f) - mu * mu;
  const float rstd = rsqrtf(var + 1e-5f);
  float o0 = (v0 - mu) * rstd * ldf(gamma, tid, f32) + ldf(beta, tid, f32);
  float o1 = (v1 - mu) * rstd * ldf(gamma, tid + 256, f32) +
             ldf(beta, tid + 256, f32);
  if (f32) {
    float* o = (float*)d_out;
    o[i0] = o0;
    o[i1] = o1;
  } else {
    __hip_bfloat16* o = (__hip_bfloat16*)d_out;
    o[i0] = __float2bfloat16(o0);
    o[i1] = __float2bfloat16(o1);
  }
}

// ---------------------------------------------------------------------------
extern "C" void kernel_launch(void* const* d_in, const int* in_sizes, int n_in,
                              void* d_out, int out_size, void* d_ws,
                              size_t ws_size, hipStream_t stream) {
  const void* query = d_in[0];
  const void* key = d_in[1];
  const void* value = d_in[2];
  const void* rbf = d_in[3];
  const int* key_mask = (const int*)d_in[4];
  const void* Wq = d_in[5];
  const void* bq = d_in[6];
  const void* Wk = d_in[7];
  const void* bk = d_in[8];
  const void* Wv = d_in[9];
  const void* bv = d_in[10];
  const void* Wr = d_in[11];
  const void* br = d_in[12];
  const void* Wo = d_in[13];
  const void* bo = d_in[14];
  const void* gamma = d_in[15];
  const void* beta = d_in[16];

  // ws: [flag 16B] Q | Kt | V | AO | Xp[2]
  int* flag = (int*)d_ws;
  float* base = (float*)d_ws + 4;
  float* Qw = base;
  float* Ktw = Qw + (size_t)BB * LL * DD;    // +524288
  float* Vw = Ktw + (size_t)BB * PP * DD;    // +2097152
  float* AO = Vw + (size_t)BB * PP * DD;     // +2097152
  float* Xp = AO + (size_t)BB * LL * DD;     // +524288 (Xp: 2x 524288)

  detect_dtype<<<1, 256, 0, stream>>>((const float*)query, flag);
  qkv_gemm<<<dim3(576), 256, 0, stream>>>(query, key, value, Wq, bq, Wk, bk,
                                          Wv, bv, Qw, Ktw, Vw, flag);
  attn_v10<<<dim3(BB * LL / 4), 512, 0, stream>>>(Qw, Ktw, Vw, rbf, Wr, br,
                                                  key_mask, AO, d_out, flag);
  proj_out<<<dim3(16, 8, 2), 256, 0, stream>>>(AO, Wo, Xp, flag);
  ln_kernel<<<dim3(BB * LL), 256, 0, stream>>>(Xp, query, bo, gamma, beta,
                                               d_out, flag);
}